// Round 1
// baseline (1501.790 us; speedup 1.0000x reference)
//
#include <hip/hip_runtime.h>
#include <math.h>

#define HID 128
#define NGAUSS 50
#define TBL 2048
#define DMAX 8.6605f

__device__ __forceinline__ float sspf(float x) {
  float ax = fabsf(x);
  return fmaxf(x, 0.0f) + log1pf(expf(-ax)) - 0.69314718055994530942f;
}

__device__ __forceinline__ void fma4(float4& a, float s, const float4& w) {
  a.x = fmaf(s, w.x, a.x);
  a.y = fmaf(s, w.y, a.y);
  a.z = fmaf(s, w.z, a.z);
  a.w = fmaf(s, w.w, a.w);
}

// ---- Build W(d) lookup table: tab[l][ti][j] = (ssp(rbf(d)@W1+b1)@W2+b2)[j] * C(d)
__global__ __launch_bounds__(128) void build_table_k(
    const float* __restrict__ w1, const float* __restrict__ b1,
    const float* __restrict__ w2, const float* __restrict__ b2,
    float* __restrict__ tab) {
  int l = blockIdx.x >> 11;          // / TBL
  int ti = blockIdx.x & (TBL - 1);
  int j = threadIdx.x;               // 0..127
  __shared__ float rbf[NGAUSS];
  __shared__ float v1[HID];
  const float step = DMAX / (float)(TBL - 1);
  float d = ti * step;
  if (j < NGAUSS) {
    const float gstep = 10.0f / 49.0f;
    const float gcoeff = -12.005f;   // -0.5/(10/49)^2
    float diff = d - j * gstep;
    rbf[j] = expf(gcoeff * diff * diff);
  }
  __syncthreads();
  float s = b1[l * HID + j];
  const float* w1p = w1 + l * NGAUSS * HID + j;
  for (int g = 0; g < NGAUSS; g++) s = fmaf(rbf[g], w1p[g * HID], s);
  v1[j] = sspf(s);
  __syncthreads();
  float s2 = b2[l * HID + j];
  const float* w2p = w2 + l * HID * HID + j;
  for (int k = 0; k < HID; k++) s2 = fmaf(v1[k], w2p[k * HID], s2);
  float C = 0.5f * (cosf(d * 0.3141592653589793f) + 1.0f);
  tab[((size_t)l * TBL + ti) * HID + j] = s2 * C;
}

// ---- h = emb[z]
__global__ __launch_bounds__(256) void emb_gather_k(
    const int* __restrict__ z, const float* __restrict__ emb,
    float* __restrict__ h, int N) {
  int i4 = blockIdx.x * 256 + threadIdx.x;   // float4 index
  if (i4 >= N * 32) return;
  int a = i4 >> 5;
  ((float4*)h)[i4] = ((const float4*)emb)[z[a] * 32 + (i4 & 31)];
}

// ---- per-edge distance + histogram of targets
__global__ __launch_bounds__(256) void edge_prep_k(
    const int* __restrict__ row, const int* __restrict__ col,
    const float* __restrict__ pos, float* __restrict__ d_e,
    int* __restrict__ counts, int E) {
  int e = blockIdx.x * 256 + threadIdx.x;
  if (e >= E) return;
  int r = row[e], c = col[e];
  float dx = pos[r * 3 + 0] - pos[c * 3 + 0];
  float dy = pos[r * 3 + 1] - pos[c * 3 + 1];
  float dz = pos[r * 3 + 2] - pos[c * 3 + 2];
  d_e[e] = sqrtf(dx * dx + dy * dy + dz * dz);
  atomicAdd(&counts[c], 1);
}

// ---- single-block exclusive scan over counts -> starts (and cursor copy)
__global__ __launch_bounds__(1024) void scan_k(
    const int* __restrict__ counts, int* __restrict__ starts,
    int* __restrict__ cursor, int n) {
  __shared__ int part[1024];
  int t = threadIdx.x;
  int chunk = (n + 1023) / 1024;
  int begin = min(t * chunk, n);
  int end = min(begin + chunk, n);
  int s = 0;
  for (int i = begin; i < end; i++) s += counts[i];
  part[t] = s;
  __syncthreads();
  for (int o = 1; o < 1024; o <<= 1) {
    int v = (t >= o) ? part[t - o] : 0;
    __syncthreads();
    part[t] += v;
    __syncthreads();
  }
  int prefix = (t == 0) ? 0 : part[t - 1];
  for (int i = begin; i < end; i++) {
    starts[i] = prefix;
    cursor[i] = prefix;
    prefix += counts[i];
  }
  if (t == 0) starts[n] = part[1023];
}

// ---- scatter edges into CSR slots: payload = {source row, d}
__global__ __launch_bounds__(256) void scatter_k(
    const int* __restrict__ row, const int* __restrict__ col,
    const float* __restrict__ d_e, int* __restrict__ cursor,
    int2* __restrict__ payload, int E) {
  int e = blockIdx.x * 256 + threadIdx.x;
  if (e >= E) return;
  int c = col[e];
  int p = atomicAdd(&cursor[c], 1);
  payload[p] = make_int2(row[e], __float_as_int(d_e[e]));
}

// ---- out[a][:] = act(in[a][:] @ W + b) (+ residual)  — N x 128 @ 128 x 128
// MODE 0: plain (no bias no act); MODE 1: bias + ssp; MODE 2: bias + residual add into out
template <int MODE>
__global__ __launch_bounds__(256) void gemm128_k(
    const float* __restrict__ in, const float* __restrict__ W,
    const float* __restrict__ bias, float* __restrict__ out, int N) {
  __shared__ float xs[64 * HID];
  int t = threadIdx.x;
  int a0 = blockIdx.x * 64;
#pragma unroll
  for (int p = 0; p < 8; p++) {
    int fi = t + p * 256;          // float4 index within tile
    int a = a0 + (fi >> 5);
    float4 v = make_float4(0.f, 0.f, 0.f, 0.f);
    if (a < N) v = ((const float4*)in)[(size_t)a * 32 + (fi & 31)];
    ((float4*)xs)[fi] = v;
  }
  __syncthreads();
  int jg = t & 31;   // channel group, j0 = 4*jg
  int ar = t >> 5;   // 0..7 -> atoms ar*8..ar*8+7
  float4 acc[8];
#pragma unroll
  for (int i = 0; i < 8; i++) acc[i] = make_float4(0.f, 0.f, 0.f, 0.f);
  const float4* Wv = (const float4*)W;
  for (int k = 0; k < HID; k += 4) {
    float4 w0 = Wv[(k + 0) * 32 + jg];
    float4 w1 = Wv[(k + 1) * 32 + jg];
    float4 w2 = Wv[(k + 2) * 32 + jg];
    float4 w3 = Wv[(k + 3) * 32 + jg];
#pragma unroll
    for (int i = 0; i < 8; i++) {
      float4 xv = *(const float4*)&xs[(ar * 8 + i) * HID + k];
      float4 a4 = acc[i];
      fma4(a4, xv.x, w0);
      fma4(a4, xv.y, w1);
      fma4(a4, xv.z, w2);
      fma4(a4, xv.w, w3);
      acc[i] = a4;
    }
  }
#pragma unroll
  for (int i = 0; i < 8; i++) {
    int a = a0 + ar * 8 + i;
    if (a >= N) continue;
    float4 r = acc[i];
    if (MODE >= 1) {
      float4 b = ((const float4*)bias)[jg];
      r.x += b.x; r.y += b.y; r.z += b.z; r.w += b.w;
    }
    if (MODE == 1) {
      r.x = sspf(r.x); r.y = sspf(r.y); r.z = sspf(r.z); r.w = sspf(r.w);
    }
    if (MODE == 2) {
      float4 prev = ((const float4*)out)[(size_t)a * 32 + jg];
      r.x += prev.x; r.y += prev.y; r.z += prev.z; r.w += prev.w;
    }
    ((float4*)out)[(size_t)a * 32 + jg] = r;
  }
}

// ---- agg[a] = sum_{e: col=a} x[row[e]] * lerp(tab, d_e)  — one wave per atom
__global__ __launch_bounds__(256) void aggregate_k(
    const int* __restrict__ starts, const int2* __restrict__ payload,
    const float* __restrict__ x, const float* __restrict__ tab,
    float* __restrict__ agg, int N) {
  int a = blockIdx.x * 4 + (threadIdx.x >> 6);
  if (a >= N) return;
  int lane = threadIdx.x & 63;
  int s = starts[a], e_end = starts[a + 1];
  const float inv_step = (float)(TBL - 1) / DMAX;
  float2 acc = make_float2(0.f, 0.f);
  const float2* xv = (const float2*)x;
  const float2* tv = (const float2*)tab;
  for (int i = s; i < e_end; i++) {
    int2 p = payload[i];
    int r = p.x;
    float d = __int_as_float(p.y);
    float tpos = d * inv_step;
    int i0 = (int)tpos;
    i0 = min(max(i0, 0), TBL - 2);
    float f = tpos - (float)i0;
    float2 w0 = tv[(size_t)i0 * 64 + lane];
    float2 w1 = tv[(size_t)i0 * 64 + 64 + lane];
    float2 wv = make_float2(fmaf(f, w1.x - w0.x, w0.x), fmaf(f, w1.y - w0.y, w0.y));
    float2 xr = xv[(size_t)r * 64 + lane];
    acc.x = fmaf(xr.x, wv.x, acc.x);
    acc.y = fmaf(xr.y, wv.y, acc.y);
  }
  ((float2*)agg)[(size_t)a * 64 + lane] = acc;
}

// ---- per-atom energy + molecule segment-sum (one wave per atom)
__global__ __launch_bounds__(256) void readout_k(
    const float* __restrict__ h, const float* __restrict__ o1w,
    const float* __restrict__ o1b, const float* __restrict__ o2w,
    const float* __restrict__ o2b, const int* __restrict__ batch,
    float* __restrict__ out, int N) {
  int a = blockIdx.x * 4 + (threadIdx.x >> 6);
  if (a >= N) return;
  int lane = threadIdx.x & 63;
  const float* hrow = h + (size_t)a * HID;
  float acc = o1b[lane];
#pragma unroll 4
  for (int k = 0; k < HID; k++) acc = fmaf(hrow[k], o1w[k * 64 + lane], acc);
  float y = sspf(acc) * o2w[lane];
#pragma unroll
  for (int off = 32; off > 0; off >>= 1) y += __shfl_down(y, off);
  if (lane == 0) atomicAdd(&out[batch[a]], y + o2b[0]);
}

extern "C" void kernel_launch(void* const* d_in, const int* in_sizes, int n_in,
                              void* d_out, int out_size, void* d_ws, size_t ws_size,
                              hipStream_t stream) {
  const int* z = (const int*)d_in[0];
  const float* pos = (const float*)d_in[1];
  const int* batch = (const int*)d_in[2];
  const int* eidx = (const int*)d_in[3];
  const float* emb = (const float*)d_in[4];
  const float* mlp1_w = (const float*)d_in[5];
  const float* mlp1_b = (const float*)d_in[6];
  const float* mlp2_w = (const float*)d_in[7];
  const float* mlp2_b = (const float*)d_in[8];
  const float* lin1_w = (const float*)d_in[9];
  const float* lin2_w = (const float*)d_in[10];
  const float* lin2_b = (const float*)d_in[11];
  const float* int_w = (const float*)d_in[12];
  const float* int_b = (const float*)d_in[13];
  const float* out1_w = (const float*)d_in[14];
  const float* out1_b = (const float*)d_in[15];
  const float* out2_w = (const float*)d_in[16];
  const float* out2_b = (const float*)d_in[17];
  float* out = (float*)d_out;

  const int N = in_sizes[0];
  const int E = in_sizes[3] / 2;
  const int* row = eidx;
  const int* col = eidx + E;

  char* ws = (char*)d_ws;
  size_t off = 0;
  auto alloc = [&](size_t bytes) -> void* {
    void* p = ws + off;
    off = (off + bytes + 255) & ~(size_t)255;
    return p;
  };
  float* h = (float*)alloc((size_t)N * HID * 4);
  float* x = (float*)alloc((size_t)N * HID * 4);
  float* agg = (float*)alloc((size_t)N * HID * 4);
  float* d_e = (float*)alloc((size_t)E * 4);
  int2* payload = (int2*)alloc((size_t)E * 8);
  int* counts = (int*)alloc((size_t)(N + 1) * 4);
  int* starts = (int*)alloc((size_t)(N + 1) * 4);
  int* cursor = (int*)alloc((size_t)N * 4);
  float* tab = (float*)alloc((size_t)3 * TBL * HID * 4);
  (void)ws_size;

  hipMemsetAsync(counts, 0, (size_t)(N + 1) * 4, stream);
  hipMemsetAsync(out, 0, (size_t)out_size * 4, stream);

  build_table_k<<<3 * TBL, 128, 0, stream>>>(mlp1_w, mlp1_b, mlp2_w, mlp2_b, tab);
  emb_gather_k<<<(N * 32 + 255) / 256, 256, 0, stream>>>(z, emb, h, N);
  edge_prep_k<<<(E + 255) / 256, 256, 0, stream>>>(row, col, pos, d_e, counts, E);
  scan_k<<<1, 1024, 0, stream>>>(counts, starts, cursor, N);
  scatter_k<<<(E + 255) / 256, 256, 0, stream>>>(row, col, d_e, cursor, payload, E);

  int gemm_grid = (N + 63) / 64;
  for (int l = 0; l < 3; l++) {
    gemm128_k<0><<<gemm_grid, 256, 0, stream>>>(h, lin1_w + (size_t)l * HID * HID, nullptr, x, N);
    aggregate_k<<<(N + 3) / 4, 256, 0, stream>>>(starts, payload, x,
                                                 tab + (size_t)l * TBL * HID, agg, N);
    gemm128_k<1><<<gemm_grid, 256, 0, stream>>>(agg, lin2_w + (size_t)l * HID * HID,
                                                lin2_b + (size_t)l * HID, x, N);
    gemm128_k<2><<<gemm_grid, 256, 0, stream>>>(x, int_w + (size_t)l * HID * HID,
                                                int_b + (size_t)l * HID, h, N);
  }
  readout_k<<<(N + 3) / 4, 256, 0, stream>>>(h, out1_w, out1_b, out2_w, out2_b, batch, out, N);
}

// Round 2
// 1091.142 us; speedup vs baseline: 1.3763x; 1.3763x over previous
//
#include <hip/hip_runtime.h>
#include <math.h>

#define HID 128
#define NGAUSS 50
#define TBL 2048
#define DMAX 8.6605f

typedef _Float16 h2 __attribute__((ext_vector_type(2)));
typedef _Float16 h4v __attribute__((ext_vector_type(4)));

__device__ __forceinline__ float sspf(float x) {
  float ax = fabsf(x);
  return fmaxf(x, 0.0f) + log1pf(expf(-ax)) - 0.69314718055994530942f;
}

__device__ __forceinline__ void fma4(float4& a, float s, const float4& w) {
  a.x = fmaf(s, w.x, a.x);
  a.y = fmaf(s, w.y, a.y);
  a.z = fmaf(s, w.z, a.z);
  a.w = fmaf(s, w.w, a.w);
}

// ---- Build W(d) lookup table: tab[l][ti][j] = (ssp(rbf(d)@W1+b1)@W2+b2)[j] * C(d)
__global__ __launch_bounds__(128) void build_table_k(
    const float* __restrict__ w1, const float* __restrict__ b1,
    const float* __restrict__ w2, const float* __restrict__ b2,
    float* __restrict__ tab) {
  int l = blockIdx.x >> 11;          // / TBL
  int ti = blockIdx.x & (TBL - 1);
  int j = threadIdx.x;               // 0..127
  __shared__ float rbf[NGAUSS];
  __shared__ float v1[HID];
  const float step = DMAX / (float)(TBL - 1);
  float d = ti * step;
  if (j < NGAUSS) {
    const float gstep = 10.0f / 49.0f;
    const float gcoeff = -12.005f;   // -0.5/(10/49)^2
    float diff = d - j * gstep;
    rbf[j] = expf(gcoeff * diff * diff);
  }
  __syncthreads();
  float s = b1[l * HID + j];
  const float* w1p = w1 + l * NGAUSS * HID + j;
  for (int g = 0; g < NGAUSS; g++) s = fmaf(rbf[g], w1p[g * HID], s);
  v1[j] = sspf(s);
  __syncthreads();
  float s2 = b2[l * HID + j];
  const float* w2p = w2 + l * HID * HID + j;
  for (int k = 0; k < HID; k++) s2 = fmaf(v1[k], w2p[k * HID], s2);
  float C = 0.5f * (cosf(d * 0.3141592653589793f) + 1.0f);
  tab[((size_t)l * TBL + ti) * HID + j] = s2 * C;
}

// ---- h = emb[z]
__global__ __launch_bounds__(256) void emb_gather_k(
    const int* __restrict__ z, const float* __restrict__ emb,
    float* __restrict__ h, int N) {
  int i4 = blockIdx.x * 256 + threadIdx.x;   // float4 index
  if (i4 >= N * 32) return;
  int a = i4 >> 5;
  ((float4*)h)[i4] = ((const float4*)emb)[z[a] * 32 + (i4 & 31)];
}

// ---- per-edge distance + histogram of targets
__global__ __launch_bounds__(256) void edge_prep_k(
    const int* __restrict__ row, const int* __restrict__ col,
    const float* __restrict__ pos, float* __restrict__ d_e,
    int* __restrict__ counts, int E) {
  int e = blockIdx.x * 256 + threadIdx.x;
  if (e >= E) return;
  int r = row[e], c = col[e];
  float dx = pos[r * 3 + 0] - pos[c * 3 + 0];
  float dy = pos[r * 3 + 1] - pos[c * 3 + 1];
  float dz = pos[r * 3 + 2] - pos[c * 3 + 2];
  d_e[e] = sqrtf(dx * dx + dy * dy + dz * dz);
  atomicAdd(&counts[c], 1);
}

// ---- 3-phase coalesced exclusive scan of counts -> starts, cursor
__global__ __launch_bounds__(256) void scan1_k(
    const int* __restrict__ counts, int* __restrict__ bsum, int N) {
  __shared__ int red[256];
  int b = blockIdx.x, t = threadIdx.x;
  int s = 0;
#pragma unroll
  for (int j = 0; j < 4; j++) {
    int i = b * 1024 + j * 256 + t;
    if (i < N) s += counts[i];
  }
  red[t] = s;
  __syncthreads();
  for (int o = 128; o > 0; o >>= 1) {
    if (t < o) red[t] += red[t + o];
    __syncthreads();
  }
  if (t == 0) bsum[b] = red[0];
}

__global__ __launch_bounds__(256) void scan2_k(
    int* __restrict__ bsum, int* __restrict__ starts, int nb, int N) {
  __shared__ int sh[256];
  int t = threadIdx.x;
  sh[t] = (t < nb) ? bsum[t] : 0;
  __syncthreads();
  for (int o = 1; o < 256; o <<= 1) {
    int v = (t >= o) ? sh[t - o] : 0;
    __syncthreads();
    sh[t] += v;
    __syncthreads();
  }
  if (t < nb) bsum[t] = (t == 0) ? 0 : sh[t - 1];   // exclusive
  if (t == 0) starts[N] = sh[255];                  // total (zeros beyond nb)
}

__global__ __launch_bounds__(256) void scan3_k(
    const int* __restrict__ counts, const int* __restrict__ bsum,
    int* __restrict__ starts, int* __restrict__ cursor, int N) {
  __shared__ int sh[256];
  int b = blockIdx.x, t = threadIdx.x;
  int base = b * 1024 + t * 4;
  int c[4];
#pragma unroll
  for (int j = 0; j < 4; j++) c[j] = (base + j < N) ? counts[base + j] : 0;
  int tsum = c[0] + c[1] + c[2] + c[3];
  sh[t] = tsum;
  __syncthreads();
  for (int o = 1; o < 256; o <<= 1) {
    int v = (t >= o) ? sh[t - o] : 0;
    __syncthreads();
    sh[t] += v;
    __syncthreads();
  }
  int p = bsum[b] + ((t == 0) ? 0 : sh[t - 1]);
#pragma unroll
  for (int j = 0; j < 4; j++) {
    if (base + j < N) {
      starts[base + j] = p;
      cursor[base + j] = p;
      p += c[j];
    }
  }
}

// ---- scatter edges into CSR slots: payload = {source row, d}
__global__ __launch_bounds__(256) void scatter_k(
    const int* __restrict__ row, const int* __restrict__ col,
    const float* __restrict__ d_e, int* __restrict__ cursor,
    int2* __restrict__ payload, int E) {
  int e = blockIdx.x * 256 + threadIdx.x;
  if (e >= E) return;
  int c = col[e];
  int p = atomicAdd(&cursor[c], 1);
  payload[p] = make_int2(row[e], __float_as_int(d_e[e]));
}

// ---- x16 = h @ lin1_w  (fp16 output, for the gather)
__global__ __launch_bounds__(256) void gemm_lin1_k(
    const float* __restrict__ in, const float* __restrict__ W,
    _Float16* __restrict__ x16, int N) {
  __shared__ float xs[64 * HID];
  int t = threadIdx.x;
  int a0 = blockIdx.x * 64;
#pragma unroll
  for (int p = 0; p < 8; p++) {
    int fi = t + p * 256;
    int a = a0 + (fi >> 5);
    float4 v = make_float4(0.f, 0.f, 0.f, 0.f);
    if (a < N) v = ((const float4*)in)[(size_t)a * 32 + (fi & 31)];
    ((float4*)xs)[fi] = v;
  }
  __syncthreads();
  int jg = t & 31;
  int ar = t >> 5;
  float4 acc[8];
#pragma unroll
  for (int i = 0; i < 8; i++) acc[i] = make_float4(0.f, 0.f, 0.f, 0.f);
  const float4* Wv = (const float4*)W;
  for (int k = 0; k < HID; k += 4) {
    float4 w0 = Wv[(k + 0) * 32 + jg];
    float4 w1 = Wv[(k + 1) * 32 + jg];
    float4 w2 = Wv[(k + 2) * 32 + jg];
    float4 w3 = Wv[(k + 3) * 32 + jg];
#pragma unroll
    for (int i = 0; i < 8; i++) {
      float4 xv = *(const float4*)&xs[(ar * 8 + i) * HID + k];
      float4 a4 = acc[i];
      fma4(a4, xv.x, w0);
      fma4(a4, xv.y, w1);
      fma4(a4, xv.z, w2);
      fma4(a4, xv.w, w3);
      acc[i] = a4;
    }
  }
#pragma unroll
  for (int i = 0; i < 8; i++) {
    int a = a0 + ar * 8 + i;
    if (a >= N) continue;
    h4v o;
    o.x = (_Float16)acc[i].x; o.y = (_Float16)acc[i].y;
    o.z = (_Float16)acc[i].z; o.w = (_Float16)acc[i].w;
    ((h4v*)x16)[(size_t)a * 32 + jg] = o;
  }
}

// ---- fused: h += (ssp(agg@W2+b2)) @ W3 + b3
__global__ __launch_bounds__(256) void fused23_k(
    const float* __restrict__ agg, const float* __restrict__ W2,
    const float* __restrict__ b2, const float* __restrict__ W3,
    const float* __restrict__ b3, float* __restrict__ h, int N) {
  __shared__ float xs[64 * HID];
  int t = threadIdx.x;
  int a0 = blockIdx.x * 64;
#pragma unroll
  for (int p = 0; p < 8; p++) {
    int fi = t + p * 256;
    int a = a0 + (fi >> 5);
    float4 v = make_float4(0.f, 0.f, 0.f, 0.f);
    if (a < N) v = ((const float4*)agg)[(size_t)a * 32 + (fi & 31)];
    ((float4*)xs)[fi] = v;
  }
  __syncthreads();
  int jg = t & 31;
  int ar = t >> 5;
  float4 acc[8];
#pragma unroll
  for (int i = 0; i < 8; i++) acc[i] = make_float4(0.f, 0.f, 0.f, 0.f);
  const float4* W2v = (const float4*)W2;
  for (int k = 0; k < HID; k += 4) {
    float4 w0 = W2v[(k + 0) * 32 + jg];
    float4 w1 = W2v[(k + 1) * 32 + jg];
    float4 w2 = W2v[(k + 2) * 32 + jg];
    float4 w3 = W2v[(k + 3) * 32 + jg];
#pragma unroll
    for (int i = 0; i < 8; i++) {
      float4 xv = *(const float4*)&xs[(ar * 8 + i) * HID + k];
      float4 a4 = acc[i];
      fma4(a4, xv.x, w0);
      fma4(a4, xv.y, w1);
      fma4(a4, xv.z, w2);
      fma4(a4, xv.w, w3);
      acc[i] = a4;
    }
  }
  float4 bb = ((const float4*)b2)[jg];
  __syncthreads();   // everyone done reading xs
#pragma unroll
  for (int i = 0; i < 8; i++) {
    float4 r = acc[i];
    r.x = sspf(r.x + bb.x); r.y = sspf(r.y + bb.y);
    r.z = sspf(r.z + bb.z); r.w = sspf(r.w + bb.w);
    *(float4*)&xs[(ar * 8 + i) * HID + jg * 4] = r;
  }
  __syncthreads();
#pragma unroll
  for (int i = 0; i < 8; i++) acc[i] = make_float4(0.f, 0.f, 0.f, 0.f);
  const float4* W3v = (const float4*)W3;
  for (int k = 0; k < HID; k += 4) {
    float4 w0 = W3v[(k + 0) * 32 + jg];
    float4 w1 = W3v[(k + 1) * 32 + jg];
    float4 w2 = W3v[(k + 2) * 32 + jg];
    float4 w3 = W3v[(k + 3) * 32 + jg];
#pragma unroll
    for (int i = 0; i < 8; i++) {
      float4 xv = *(const float4*)&xs[(ar * 8 + i) * HID + k];
      float4 a4 = acc[i];
      fma4(a4, xv.x, w0);
      fma4(a4, xv.y, w1);
      fma4(a4, xv.z, w2);
      fma4(a4, xv.w, w3);
      acc[i] = a4;
    }
  }
  float4 b3v = ((const float4*)b3)[jg];
#pragma unroll
  for (int i = 0; i < 8; i++) {
    int a = a0 + ar * 8 + i;
    if (a >= N) continue;
    float4 prev = ((const float4*)h)[(size_t)a * 32 + jg];
    float4 r = acc[i];
    r.x += b3v.x + prev.x; r.y += b3v.y + prev.y;
    r.z += b3v.z + prev.z; r.w += b3v.w + prev.w;
    ((float4*)h)[(size_t)a * 32 + jg] = r;
  }
}

// ---- agg[a] = sum_{e: col=a} x16[row[e]] * lerp(tab, d_e) — one wave per atom, 4x unroll
__global__ __launch_bounds__(256) void aggregate_k(
    const int* __restrict__ starts, const int2* __restrict__ payload,
    const _Float16* __restrict__ x16, const float* __restrict__ tab,
    float* __restrict__ agg, int N) {
  int a = blockIdx.x * 4 + (threadIdx.x >> 6);
  if (a >= N) return;
  int lane = threadIdx.x & 63;
  int s = starts[a], e_end = starts[a + 1];
  const float inv_step = (float)(TBL - 1) / DMAX;
  float2 acc = make_float2(0.f, 0.f);
  const float2* tv = (const float2*)tab;
  const h2* xv = (const h2*)x16;
  const int4* pp = (const int4*)payload;

  int i = s;
  // peel to even alignment for int4 payload loads
  if ((i & 1) && i < e_end) {
    int2 p = payload[i];
    float tp = __int_as_float(p.y) * inv_step;
    int i0 = min((int)tp, TBL - 2);
    float f = tp - (float)i0;
    float2 w0 = tv[(size_t)i0 * 64 + lane];
    float2 w1 = tv[(size_t)i0 * 64 + 64 + lane];
    h2 xr = xv[(size_t)p.x * 64 + lane];
    float wx = fmaf(f, w1.x - w0.x, w0.x);
    float wy = fmaf(f, w1.y - w0.y, w0.y);
    acc.x = fmaf((float)xr.x, wx, acc.x);
    acc.y = fmaf((float)xr.y, wy, acc.y);
    i++;
  }
  for (; i + 4 <= e_end; i += 4) {
    int4 q0 = pp[i >> 1];
    int4 q1 = pp[(i >> 1) + 1];
    // edge 0: (q0.x row, q0.y d) ... edge 3: (q1.z, q1.w)
    float tp0 = __int_as_float(q0.y) * inv_step;
    float tp1 = __int_as_float(q0.w) * inv_step;
    float tp2 = __int_as_float(q1.y) * inv_step;
    float tp3 = __int_as_float(q1.w) * inv_step;
    int i00 = min((int)tp0, TBL - 2);
    int i01 = min((int)tp1, TBL - 2);
    int i02 = min((int)tp2, TBL - 2);
    int i03 = min((int)tp3, TBL - 2);
    float f0 = tp0 - (float)i00, f1 = tp1 - (float)i01;
    float f2 = tp2 - (float)i02, f3 = tp3 - (float)i03;
    float2 wa0 = tv[(size_t)i00 * 64 + lane], wb0 = tv[(size_t)i00 * 64 + 64 + lane];
    float2 wa1 = tv[(size_t)i01 * 64 + lane], wb1 = tv[(size_t)i01 * 64 + 64 + lane];
    float2 wa2 = tv[(size_t)i02 * 64 + lane], wb2 = tv[(size_t)i02 * 64 + 64 + lane];
    float2 wa3 = tv[(size_t)i03 * 64 + lane], wb3 = tv[(size_t)i03 * 64 + 64 + lane];
    h2 x0 = xv[(size_t)q0.x * 64 + lane];
    h2 x1 = xv[(size_t)q0.z * 64 + lane];
    h2 x2 = xv[(size_t)q1.x * 64 + lane];
    h2 x3 = xv[(size_t)q1.z * 64 + lane];
    float wx, wy;
    wx = fmaf(f0, wb0.x - wa0.x, wa0.x); wy = fmaf(f0, wb0.y - wa0.y, wa0.y);
    acc.x = fmaf((float)x0.x, wx, acc.x); acc.y = fmaf((float)x0.y, wy, acc.y);
    wx = fmaf(f1, wb1.x - wa1.x, wa1.x); wy = fmaf(f1, wb1.y - wa1.y, wa1.y);
    acc.x = fmaf((float)x1.x, wx, acc.x); acc.y = fmaf((float)x1.y, wy, acc.y);
    wx = fmaf(f2, wb2.x - wa2.x, wa2.x); wy = fmaf(f2, wb2.y - wa2.y, wa2.y);
    acc.x = fmaf((float)x2.x, wx, acc.x); acc.y = fmaf((float)x2.y, wy, acc.y);
    wx = fmaf(f3, wb3.x - wa3.x, wa3.x); wy = fmaf(f3, wb3.y - wa3.y, wa3.y);
    acc.x = fmaf((float)x3.x, wx, acc.x); acc.y = fmaf((float)x3.y, wy, acc.y);
  }
  for (; i < e_end; i++) {
    int2 p = payload[i];
    float tp = __int_as_float(p.y) * inv_step;
    int i0 = min((int)tp, TBL - 2);
    float f = tp - (float)i0;
    float2 w0 = tv[(size_t)i0 * 64 + lane];
    float2 w1 = tv[(size_t)i0 * 64 + 64 + lane];
    h2 xr = xv[(size_t)p.x * 64 + lane];
    float wx = fmaf(f, w1.x - w0.x, w0.x);
    float wy = fmaf(f, w1.y - w0.y, w0.y);
    acc.x = fmaf((float)xr.x, wx, acc.x);
    acc.y = fmaf((float)xr.y, wy, acc.y);
  }
  ((float2*)agg)[(size_t)a * 64 + lane] = acc;
}

// ---- per-atom energy: e[a] = ssp(h[a]@o1w + o1b) . o2w   (64 atoms / block)
__global__ __launch_bounds__(256) void atom_energy_k(
    const float* __restrict__ h, const float* __restrict__ o1w,
    const float* __restrict__ o1b, const float* __restrict__ o2w,
    float* __restrict__ e, int N) {
  __shared__ float xs[64 * HID];
  int t = threadIdx.x;
  int a0 = blockIdx.x * 64;
#pragma unroll
  for (int p = 0; p < 8; p++) {
    int fi = t + p * 256;
    int a = a0 + (fi >> 5);
    float4 v = make_float4(0.f, 0.f, 0.f, 0.f);
    if (a < N) v = ((const float4*)h)[(size_t)a * 32 + (fi & 31)];
    ((float4*)xs)[fi] = v;
  }
  __syncthreads();
  int jg = t & 15;   // channel group of 4 within [0,64)
  int ar = t >> 4;   // 0..15 -> atoms ar*4 .. ar*4+3
  float4 acc[4];
#pragma unroll
  for (int i = 0; i < 4; i++) acc[i] = make_float4(0.f, 0.f, 0.f, 0.f);
  const float4* Wv = (const float4*)o1w;   // 128 rows x 16 float4
  for (int k = 0; k < HID; k += 4) {
    float4 w0 = Wv[(k + 0) * 16 + jg];
    float4 w1 = Wv[(k + 1) * 16 + jg];
    float4 w2 = Wv[(k + 2) * 16 + jg];
    float4 w3 = Wv[(k + 3) * 16 + jg];
#pragma unroll
    for (int i = 0; i < 4; i++) {
      float4 xv = *(const float4*)&xs[(ar * 4 + i) * HID + k];
      float4 a4 = acc[i];
      fma4(a4, xv.x, w0);
      fma4(a4, xv.y, w1);
      fma4(a4, xv.z, w2);
      fma4(a4, xv.w, w3);
      acc[i] = a4;
    }
  }
  float4 b = ((const float4*)o1b)[jg];
  float4 ow = ((const float4*)o2w)[jg];
#pragma unroll
  for (int i = 0; i < 4; i++) {
    float4 v = acc[i];
    float y = sspf(v.x + b.x) * ow.x + sspf(v.y + b.y) * ow.y +
              sspf(v.z + b.z) * ow.z + sspf(v.w + b.w) * ow.w;
    y += __shfl_xor(y, 1);
    y += __shfl_xor(y, 2);
    y += __shfl_xor(y, 4);
    y += __shfl_xor(y, 8);
    int a = a0 + ar * 4 + i;
    if (jg == 0 && a < N) e[a] = y;
  }
}

// ---- molecule segment-sum
__global__ __launch_bounds__(256) void seg_sum_k(
    const float* __restrict__ e, const int* __restrict__ batch,
    const float* __restrict__ o2b, float* __restrict__ out, int N) {
  int a = blockIdx.x * 256 + threadIdx.x;
  if (a >= N) return;
  atomicAdd(&out[batch[a]], e[a] + o2b[0]);
}

extern "C" void kernel_launch(void* const* d_in, const int* in_sizes, int n_in,
                              void* d_out, int out_size, void* d_ws, size_t ws_size,
                              hipStream_t stream) {
  const int* z = (const int*)d_in[0];
  const float* pos = (const float*)d_in[1];
  const int* batch = (const int*)d_in[2];
  const int* eidx = (const int*)d_in[3];
  const float* emb = (const float*)d_in[4];
  const float* mlp1_w = (const float*)d_in[5];
  const float* mlp1_b = (const float*)d_in[6];
  const float* mlp2_w = (const float*)d_in[7];
  const float* mlp2_b = (const float*)d_in[8];
  const float* lin1_w = (const float*)d_in[9];
  const float* lin2_w = (const float*)d_in[10];
  const float* lin2_b = (const float*)d_in[11];
  const float* int_w = (const float*)d_in[12];
  const float* int_b = (const float*)d_in[13];
  const float* out1_w = (const float*)d_in[14];
  const float* out1_b = (const float*)d_in[15];
  const float* out2_w = (const float*)d_in[16];
  const float* out2_b = (const float*)d_in[17];
  float* out = (float*)d_out;

  const int N = in_sizes[0];
  const int E = in_sizes[3] / 2;
  const int* row = eidx;
  const int* col = eidx + E;

  char* ws = (char*)d_ws;
  size_t off = 0;
  auto alloc = [&](size_t bytes) -> void* {
    void* p = ws + off;
    off = (off + bytes + 255) & ~(size_t)255;
    return p;
  };
  float* h = (float*)alloc((size_t)N * HID * 4);
  _Float16* x16 = (_Float16*)alloc((size_t)N * HID * 2);
  float* agg = (float*)alloc((size_t)N * HID * 4);
  float* d_e = (float*)alloc((size_t)E * 4);
  int2* payload = (int2*)alloc((size_t)E * 8 + 16);   // +16: int4 tail overread safety
  int* counts = (int*)alloc((size_t)(N + 1) * 4);
  int* starts = (int*)alloc((size_t)(N + 1) * 4);
  int* cursor = (int*)alloc((size_t)N * 4);
  float* tab = (float*)alloc((size_t)3 * TBL * HID * 4);
  float* e_atom = (float*)alloc((size_t)N * 4);
  int* bsum = (int*)alloc(1024);
  (void)ws_size;

  hipMemsetAsync(counts, 0, (size_t)(N + 1) * 4, stream);
  hipMemsetAsync(out, 0, (size_t)out_size * 4, stream);

  const int nb = (N + 1023) / 1024;
  build_table_k<<<3 * TBL, 128, 0, stream>>>(mlp1_w, mlp1_b, mlp2_w, mlp2_b, tab);
  emb_gather_k<<<(N * 32 + 255) / 256, 256, 0, stream>>>(z, emb, h, N);
  edge_prep_k<<<(E + 255) / 256, 256, 0, stream>>>(row, col, pos, d_e, counts, E);
  scan1_k<<<nb, 256, 0, stream>>>(counts, bsum, N);
  scan2_k<<<1, 256, 0, stream>>>(bsum, starts, nb, N);
  scan3_k<<<nb, 256, 0, stream>>>(counts, bsum, starts, cursor, N);
  scatter_k<<<(E + 255) / 256, 256, 0, stream>>>(row, col, d_e, cursor, payload, E);

  int gemm_grid = (N + 63) / 64;
  for (int l = 0; l < 3; l++) {
    gemm_lin1_k<<<gemm_grid, 256, 0, stream>>>(h, lin1_w + (size_t)l * HID * HID, x16, N);
    aggregate_k<<<(N + 3) / 4, 256, 0, stream>>>(starts, payload, x16,
                                                 tab + (size_t)l * TBL * HID, agg, N);
    fused23_k<<<gemm_grid, 256, 0, stream>>>(agg, lin2_w + (size_t)l * HID * HID,
                                             lin2_b + (size_t)l * HID,
                                             int_w + (size_t)l * HID * HID,
                                             int_b + (size_t)l * HID, h, N);
  }
  atom_energy_k<<<gemm_grid, 256, 0, stream>>>(h, out1_w, out1_b, out2_w, e_atom, N);
  seg_sum_k<<<(N + 255) / 256, 256, 0, stream>>>(e_atom, batch, out2_b, out, N);
}

// Round 4
// 849.134 us; speedup vs baseline: 1.7686x; 1.2850x over previous
//
#include <hip/hip_runtime.h>
#include <math.h>

#define HID 128
#define NGAUSS 50
#define TBL 2048
#define DMAX 8.6605f
#define LDX 136   // fp16 row pitch for MFMA LDS tiles (pad 8 halves)

typedef _Float16 h2 __attribute__((ext_vector_type(2)));
typedef _Float16 h4v __attribute__((ext_vector_type(4)));
typedef _Float16 f16x8 __attribute__((ext_vector_type(8)));
typedef float f32x4 __attribute__((ext_vector_type(4)));

__device__ __forceinline__ float sspf(float x) {
  float ax = fabsf(x);
  return fmaxf(x, 0.0f) + log1pf(expf(-ax)) - 0.69314718055994530942f;
}

__device__ __forceinline__ void fma4(float4& a, float s, const float4& w) {
  a.x = fmaf(s, w.x, a.x);
  a.y = fmaf(s, w.y, a.y);
  a.z = fmaf(s, w.z, a.z);
  a.w = fmaf(s, w.w, a.w);
}

// ---- Build W(d) lookup table: tab[l][ti][j] = (ssp(rbf(d)@W1+b1)@W2+b2)[j] * C(d)
__global__ __launch_bounds__(128) void build_table_k(
    const float* __restrict__ w1, const float* __restrict__ b1,
    const float* __restrict__ w2, const float* __restrict__ b2,
    float* __restrict__ tab) {
  int l = blockIdx.x >> 11;
  int ti = blockIdx.x & (TBL - 1);
  int j = threadIdx.x;
  __shared__ float rbf[NGAUSS];
  __shared__ float v1[HID];
  const float step = DMAX / (float)(TBL - 1);
  float d = ti * step;
  if (j < NGAUSS) {
    const float gstep = 10.0f / 49.0f;
    const float gcoeff = -12.005f;
    float diff = d - j * gstep;
    rbf[j] = expf(gcoeff * diff * diff);
  }
  __syncthreads();
  float s = b1[l * HID + j];
  const float* w1p = w1 + l * NGAUSS * HID + j;
  for (int g = 0; g < NGAUSS; g++) s = fmaf(rbf[g], w1p[g * HID], s);
  v1[j] = sspf(s);
  __syncthreads();
  float s2 = b2[l * HID + j];
  const float* w2p = w2 + l * HID * HID + j;
  for (int k = 0; k < HID; k++) s2 = fmaf(v1[k], w2p[k * HID], s2);
  float C = 0.5f * (cosf(d * 0.3141592653589793f) + 1.0f);
  tab[((size_t)l * TBL + ti) * HID + j] = s2 * C;
}

// ---- tab2[l][i][lane] = (tab[i][2l..], tab[i+1][2l..]) paired for 1-load lerp
__global__ __launch_bounds__(256) void pair_table_k(
    const float* __restrict__ tab, float4* __restrict__ tab2) {
  int idx = blockIdx.x * 256 + threadIdx.x;
  if (idx >= 3 * TBL * 64) return;
  int lane = idx & 63;
  int i = (idx >> 6) & (TBL - 1);
  int l = idx >> 17;
  int i1 = min(i + 1, TBL - 1);
  const float* r0 = tab + ((size_t)l * TBL + i) * HID + lane * 2;
  const float* r1 = tab + ((size_t)l * TBL + i1) * HID + lane * 2;
  tab2[idx] = make_float4(r0[0], r0[1], r1[0], r1[1]);
}

// ---- transpose+convert the 9 128x128 weight matrices to fp16 Wt[n][k]
__global__ __launch_bounds__(256) void wtrans9_k(
    const float* __restrict__ lin1, const float* __restrict__ lin2,
    const float* __restrict__ intw, _Float16* __restrict__ out) {
  int b = blockIdx.x;  // 0..8
  const float* src = (b < 3 ? lin1 : (b < 6 ? lin2 : intw)) + (size_t)(b % 3) * HID * HID;
  _Float16* dst = out + (size_t)b * HID * HID;
  __shared__ _Float16 tile[128 * 130];
  int t = threadIdx.x;
  // tile[k][n] = src[k][n], coalesced read
  for (int i = t; i < HID * HID; i += 256) tile[(i >> 7) * 130 + (i & 127)] = (_Float16)src[i];
  __syncthreads();
  // dst[n][k] = tile[k][n], coalesced write
  for (int i = t; i < HID * HID; i += 256) dst[i] = tile[(i & 127) * 130 + (i >> 7)];
}

// ---- h = emb[z]
__global__ __launch_bounds__(256) void emb_gather_k(
    const int* __restrict__ z, const float* __restrict__ emb,
    float* __restrict__ h, int N) {
  int i4 = blockIdx.x * 256 + threadIdx.x;
  if (i4 >= N * 32) return;
  int a = i4 >> 5;
  ((float4*)h)[i4] = ((const float4*)emb)[z[a] * 32 + (i4 & 31)];
}

// ---- per-edge distance -> fixed-point table pos + histogram of targets
__global__ __launch_bounds__(256) void edge_prep_k(
    const int* __restrict__ row, const int* __restrict__ col,
    const float* __restrict__ pos, int* __restrict__ tq,
    int* __restrict__ counts, int E) {
  int e = blockIdx.x * 256 + threadIdx.x;
  if (e >= E) return;
  int r = row[e], c = col[e];
  float dx = pos[r * 3 + 0] - pos[c * 3 + 0];
  float dy = pos[r * 3 + 1] - pos[c * 3 + 1];
  float dz = pos[r * 3 + 2] - pos[c * 3 + 2];
  float d = sqrtf(dx * dx + dy * dy + dz * dz);
  const float inv_step = (float)(TBL - 1) / DMAX;
  int q = (int)(d * inv_step * 32.0f);
  tq[e] = min(q, 2046 * 32 + 31);
  atomicAdd(&counts[c], 1);
}

// ---- 3-phase coalesced exclusive scan
__global__ __launch_bounds__(256) void scan1_k(
    const int* __restrict__ counts, int* __restrict__ bsum, int N) {
  __shared__ int red[256];
  int b = blockIdx.x, t = threadIdx.x;
  int s = 0;
#pragma unroll
  for (int j = 0; j < 4; j++) {
    int i = b * 1024 + j * 256 + t;
    if (i < N) s += counts[i];
  }
  red[t] = s;
  __syncthreads();
  for (int o = 128; o > 0; o >>= 1) {
    if (t < o) red[t] += red[t + o];
    __syncthreads();
  }
  if (t == 0) bsum[b] = red[0];
}

__global__ __launch_bounds__(256) void scan2_k(
    int* __restrict__ bsum, int* __restrict__ starts, int nb, int N) {
  __shared__ int sh[256];
  int t = threadIdx.x;
  sh[t] = (t < nb) ? bsum[t] : 0;
  __syncthreads();
  for (int o = 1; o < 256; o <<= 1) {
    int v = (t >= o) ? sh[t - o] : 0;
    __syncthreads();
    sh[t] += v;
    __syncthreads();
  }
  if (t < nb) bsum[t] = (t == 0) ? 0 : sh[t - 1];
  if (t == 0) starts[N] = sh[255];
}

__global__ __launch_bounds__(256) void scan3_k(
    const int* __restrict__ counts, const int* __restrict__ bsum,
    int* __restrict__ starts, int* __restrict__ cursor, int N) {
  __shared__ int sh[256];
  int b = blockIdx.x, t = threadIdx.x;
  int base = b * 1024 + t * 4;
  int c[4];
#pragma unroll
  for (int j = 0; j < 4; j++) c[j] = (base + j < N) ? counts[base + j] : 0;
  int tsum = c[0] + c[1] + c[2] + c[3];
  sh[t] = tsum;
  __syncthreads();
  for (int o = 1; o < 256; o <<= 1) {
    int v = (t >= o) ? sh[t - o] : 0;
    __syncthreads();
    sh[t] += v;
    __syncthreads();
  }
  int p = bsum[b] + ((t == 0) ? 0 : sh[t - 1]);
#pragma unroll
  for (int j = 0; j < 4; j++) {
    if (base + j < N) {
      starts[base + j] = p;
      cursor[base + j] = p;
      p += c[j];
    }
  }
}

// ---- scatter: payload = (row<<16) | tq   (N < 65536, tq < 65536)
__global__ __launch_bounds__(256) void scatter_k(
    const int* __restrict__ row, const int* __restrict__ col,
    const int* __restrict__ tq, int* __restrict__ cursor,
    unsigned int* __restrict__ payload, int E) {
  int e = blockIdx.x * 256 + threadIdx.x;
  if (e >= E) return;
  int c = col[e];
  int p = atomicAdd(&cursor[c], 1);
  payload[p] = ((unsigned int)row[e] << 16) | (unsigned int)tq[e];
}

// ---- MFMA GEMM: x16[a][:] = (fp16)(h[a][:] @ W)   W pre-transposed fp16 Wt[n][k]
__global__ __launch_bounds__(256) void mfma_lin1_k(
    const float* __restrict__ in, const _Float16* __restrict__ Wt,
    _Float16* __restrict__ x16, int N) {
  __shared__ __align__(16) _Float16 Xs[64 * LDX];
  __shared__ __align__(16) _Float16 Ws[128 * LDX];
  int t = threadIdx.x;
  int a0 = blockIdx.x * 64;
#pragma unroll
  for (int p = 0; p < 8; p++) {
    int fi = t + p * 256;          // 2048 float4 slots of X (64x128 fp32)
    int a = fi >> 5, kg = fi & 31;
    float4 v = make_float4(0.f, 0.f, 0.f, 0.f);
    if (a0 + a < N) v = ((const float4*)in)[(size_t)(a0 + a) * 32 + kg];
    h4v o;
    o.x = (_Float16)v.x; o.y = (_Float16)v.y;
    o.z = (_Float16)v.z; o.w = (_Float16)v.w;
    *(h4v*)&Xs[a * LDX + kg * 4] = o;
  }
#pragma unroll
  for (int p = 0; p < 8; p++) {
    int si = t + p * 256;          // 2048 16B chunks (8 halves) of Wt (128x128 fp16)
    int n = si >> 4, kg = si & 15;
    *(uint4*)&Ws[n * LDX + kg * 8] = ((const uint4*)Wt)[si];
  }
  __syncthreads();
  int lane = t & 63;
  int w = t >> 6;
  int mrow = lane & 15, quad = lane >> 4;
  f32x4 zero = {0.f, 0.f, 0.f, 0.f};
  f32x4 acc[8];
#pragma unroll
  for (int i = 0; i < 8; i++) acc[i] = zero;
#pragma unroll
  for (int kk = 0; kk < 4; kk++) {
    f16x8 af = *(const f16x8*)&Xs[(w * 16 + mrow) * LDX + kk * 32 + quad * 8];
#pragma unroll
    for (int nt = 0; nt < 8; nt++) {
      f16x8 bf = *(const f16x8*)&Ws[(nt * 16 + mrow) * LDX + kk * 32 + quad * 8];
      acc[nt] = __builtin_amdgcn_mfma_f32_16x16x32_f16(af, bf, acc[nt], 0, 0, 0);
    }
  }
  __syncthreads();
#pragma unroll
  for (int nt = 0; nt < 8; nt++)
#pragma unroll
    for (int r = 0; r < 4; r++)
      Xs[(w * 16 + quad * 4 + r) * LDX + nt * 16 + mrow] = (_Float16)acc[nt][r];
  __syncthreads();
#pragma unroll
  for (int p = 0; p < 4; p++) {
    int ci = t + p * 256;          // 1024 16B chunks of out (64x128 fp16)
    int a = ci >> 4, kg = ci & 15;
    if (a0 + a < N)
      ((uint4*)x16)[(size_t)(a0 + a) * 16 + kg] = *(uint4*)&Xs[a * LDX + kg * 8];
  }
}

// ---- MFMA fused: h += ssp(agg16 @ W2 + b2) @ W3 + b3
__global__ __launch_bounds__(256) void mfma_fused23_k(
    const _Float16* __restrict__ agg16, const _Float16* __restrict__ W2t,
    const float* __restrict__ b2, const _Float16* __restrict__ W3t,
    const float* __restrict__ b3, float* __restrict__ h, int N) {
  __shared__ __align__(16) _Float16 Xs[64 * LDX];
  __shared__ __align__(16) _Float16 Ws[128 * LDX];
  int t = threadIdx.x;
  int a0 = blockIdx.x * 64;
#pragma unroll
  for (int p = 0; p < 4; p++) {
    int ci = t + p * 256;          // 1024 16B chunks of agg16 tile
    int a = ci >> 4, kg = ci & 15;
    uint4 v = make_uint4(0, 0, 0, 0);
    if (a0 + a < N) v = ((const uint4*)agg16)[(size_t)(a0 + a) * 16 + kg];
    *(uint4*)&Xs[a * LDX + kg * 8] = v;
  }
#pragma unroll
  for (int p = 0; p < 8; p++) {
    int si = t + p * 256;
    int n = si >> 4, kg = si & 15;
    *(uint4*)&Ws[n * LDX + kg * 8] = ((const uint4*)W2t)[si];
  }
  __syncthreads();
  int lane = t & 63;
  int w = t >> 6;
  int mrow = lane & 15, quad = lane >> 4;
  f32x4 zero = {0.f, 0.f, 0.f, 0.f};
  f32x4 acc[8];
#pragma unroll
  for (int i = 0; i < 8; i++) acc[i] = zero;
#pragma unroll
  for (int kk = 0; kk < 4; kk++) {
    f16x8 af = *(const f16x8*)&Xs[(w * 16 + mrow) * LDX + kk * 32 + quad * 8];
#pragma unroll
    for (int nt = 0; nt < 8; nt++) {
      f16x8 bf = *(const f16x8*)&Ws[(nt * 16 + mrow) * LDX + kk * 32 + quad * 8];
      acc[nt] = __builtin_amdgcn_mfma_f32_16x16x32_f16(af, bf, acc[nt], 0, 0, 0);
    }
  }
  float b2r[8];
#pragma unroll
  for (int nt = 0; nt < 8; nt++) b2r[nt] = b2[nt * 16 + mrow];
  __syncthreads();   // all waves done with Xs/Ws reads
  // epilogue 1: ssp(acc+b2) -> Xs (becomes GEMM2's A); restage Ws <- W3t
#pragma unroll
  for (int nt = 0; nt < 8; nt++)
#pragma unroll
    for (int r = 0; r < 4; r++)
      Xs[(w * 16 + quad * 4 + r) * LDX + nt * 16 + mrow] = (_Float16)sspf(acc[nt][r] + b2r[nt]);
#pragma unroll
  for (int p = 0; p < 8; p++) {
    int si = t + p * 256;
    int n = si >> 4, kg = si & 15;
    *(uint4*)&Ws[n * LDX + kg * 8] = ((const uint4*)W3t)[si];
  }
  __syncthreads();
#pragma unroll
  for (int i = 0; i < 8; i++) acc[i] = zero;
#pragma unroll
  for (int kk = 0; kk < 4; kk++) {
    f16x8 af = *(const f16x8*)&Xs[(w * 16 + mrow) * LDX + kk * 32 + quad * 8];
#pragma unroll
    for (int nt = 0; nt < 8; nt++) {
      f16x8 bf = *(const f16x8*)&Ws[(nt * 16 + mrow) * LDX + kk * 32 + quad * 8];
      acc[nt] = __builtin_amdgcn_mfma_f32_16x16x32_f16(af, bf, acc[nt], 0, 0, 0);
    }
  }
  float b3r[8];
#pragma unroll
  for (int nt = 0; nt < 8; nt++) b3r[nt] = b3[nt * 16 + mrow];
#pragma unroll
  for (int nt = 0; nt < 8; nt++)
#pragma unroll
    for (int r = 0; r < 4; r++) {
      int a = a0 + w * 16 + quad * 4 + r;
      if (a < N) {
        size_t idx = (size_t)a * HID + nt * 16 + mrow;
        h[idx] += acc[nt][r] + b3r[nt];
      }
    }
}

// ---- agg16[a] = (fp16) sum_{e: col=a} x16[row_e] * lerp(tab2, tq_e)
__global__ __launch_bounds__(256) void aggregate_k(
    const int* __restrict__ starts, const unsigned int* __restrict__ payload,
    const _Float16* __restrict__ x16, const float4* __restrict__ tab2,
    _Float16* __restrict__ agg16, int N) {
  int a = blockIdx.x * 4 + (threadIdx.x >> 6);
  if (a >= N) return;
  int lane = threadIdx.x & 63;
  int s = starts[a], e_end = starts[a + 1];
  float2 acc = make_float2(0.f, 0.f);
  const h2* xv = (const h2*)x16;
  auto do_edge = [&](unsigned int p) {
    int r = p >> 16;
    int i0 = (p >> 5) & 2047;
    float f = (float)(int)(p & 31) * 0.03125f;
    float4 q = tab2[(size_t)i0 * 64 + lane];
    h2 xr = xv[(size_t)r * 64 + lane];
    float wx = fmaf(f, q.z - q.x, q.x);
    float wy = fmaf(f, q.w - q.y, q.y);
    acc.x = fmaf((float)xr.x, wx, acc.x);
    acc.y = fmaf((float)xr.y, wy, acc.y);
  };
  int i = s;
  while ((i & 3) && i < e_end) { do_edge(payload[i]); i++; }
  const uint4* pp = (const uint4*)payload;
  for (; i + 8 <= e_end; i += 8) {
    uint4 q0 = pp[i >> 2];
    uint4 q1 = pp[(i >> 2) + 1];
    do_edge(q0.x); do_edge(q0.y); do_edge(q0.z); do_edge(q0.w);
    do_edge(q1.x); do_edge(q1.y); do_edge(q1.z); do_edge(q1.w);
  }
  for (; i < e_end; i++) do_edge(payload[i]);
  h2 o; o.x = (_Float16)acc.x; o.y = (_Float16)acc.y;
  ((h2*)agg16)[(size_t)a * 64 + lane] = o;
}

// ---- per-atom energy: e[a] = ssp(h[a]@o1w + o1b) . o2w
__global__ __launch_bounds__(256) void atom_energy_k(
    const float* __restrict__ h, const float* __restrict__ o1w,
    const float* __restrict__ o1b, const float* __restrict__ o2w,
    float* __restrict__ e, int N) {
  __shared__ float xs[64 * HID];
  int t = threadIdx.x;
  int a0 = blockIdx.x * 64;
#pragma unroll
  for (int p = 0; p < 8; p++) {
    int fi = t + p * 256;
    int a = a0 + (fi >> 5);
    float4 v = make_float4(0.f, 0.f, 0.f, 0.f);
    if (a < N) v = ((const float4*)h)[(size_t)a * 32 + (fi & 31)];
    ((float4*)xs)[fi] = v;
  }
  __syncthreads();
  int jg = t & 15;
  int ar = t >> 4;
  float4 acc[4];
#pragma unroll
  for (int i = 0; i < 4; i++) acc[i] = make_float4(0.f, 0.f, 0.f, 0.f);
  const float4* Wv = (const float4*)o1w;
  for (int k = 0; k < HID; k += 4) {
    float4 w0 = Wv[(k + 0) * 16 + jg];
    float4 w1 = Wv[(k + 1) * 16 + jg];
    float4 w2 = Wv[(k + 2) * 16 + jg];
    float4 w3 = Wv[(k + 3) * 16 + jg];
#pragma unroll
    for (int i = 0; i < 4; i++) {
      float4 xv = *(const float4*)&xs[(ar * 4 + i) * HID + k];
      float4 a4 = acc[i];
      fma4(a4, xv.x, w0);
      fma4(a4, xv.y, w1);
      fma4(a4, xv.z, w2);
      fma4(a4, xv.w, w3);
      acc[i] = a4;
    }
  }
  float4 b = ((const float4*)o1b)[jg];
  float4 ow = ((const float4*)o2w)[jg];
#pragma unroll
  for (int i = 0; i < 4; i++) {
    float4 v = acc[i];
    float y = sspf(v.x + b.x) * ow.x + sspf(v.y + b.y) * ow.y +
              sspf(v.z + b.z) * ow.z + sspf(v.w + b.w) * ow.w;
    y += __shfl_xor(y, 1);
    y += __shfl_xor(y, 2);
    y += __shfl_xor(y, 4);
    y += __shfl_xor(y, 8);
    int a = a0 + ar * 4 + i;
    if (jg == 0 && a < N) e[a] = y;
  }
}

__global__ __launch_bounds__(256) void seg_sum_k(
    const float* __restrict__ e, const int* __restrict__ batch,
    const float* __restrict__ o2b, float* __restrict__ out, int N) {
  int a = blockIdx.x * 256 + threadIdx.x;
  if (a >= N) return;
  atomicAdd(&out[batch[a]], e[a] + o2b[0]);
}

extern "C" void kernel_launch(void* const* d_in, const int* in_sizes, int n_in,
                              void* d_out, int out_size, void* d_ws, size_t ws_size,
                              hipStream_t stream) {
  const int* z = (const int*)d_in[0];
  const float* pos = (const float*)d_in[1];
  const int* batch = (const int*)d_in[2];
  const int* eidx = (const int*)d_in[3];
  const float* emb = (const float*)d_in[4];
  const float* mlp1_w = (const float*)d_in[5];
  const float* mlp1_b = (const float*)d_in[6];
  const float* mlp2_w = (const float*)d_in[7];
  const float* mlp2_b = (const float*)d_in[8];
  const float* lin1_w = (const float*)d_in[9];
  const float* lin2_w = (const float*)d_in[10];
  const float* lin2_b = (const float*)d_in[11];
  const float* int_w = (const float*)d_in[12];
  const float* int_b = (const float*)d_in[13];
  const float* out1_w = (const float*)d_in[14];
  const float* out1_b = (const float*)d_in[15];
  const float* out2_w = (const float*)d_in[16];
  const float* out2_b = (const float*)d_in[17];
  float* out = (float*)d_out;

  const int N = in_sizes[0];
  const int E = in_sizes[3] / 2;
  const int* row = eidx;
  const int* col = eidx + E;

  char* ws = (char*)d_ws;
  size_t off = 0;
  auto alloc = [&](size_t bytes) -> void* {
    void* p = ws + off;
    off = (off + bytes + 255) & ~(size_t)255;
    return p;
  };
  float* h = (float*)alloc((size_t)N * HID * 4);
  _Float16* x16 = (_Float16*)alloc((size_t)N * HID * 2);
  _Float16* agg16 = (_Float16*)alloc((size_t)N * HID * 2);
  int* tq = (int*)alloc((size_t)E * 4);
  unsigned int* payload = (unsigned int*)alloc((size_t)E * 4 + 16);
  int* counts = (int*)alloc((size_t)(N + 1) * 4);
  int* starts = (int*)alloc((size_t)(N + 1) * 4);
  int* cursor = (int*)alloc((size_t)N * 4);
  float* tab = (float*)alloc((size_t)3 * TBL * HID * 4);
  float4* tab2 = (float4*)alloc((size_t)3 * TBL * 64 * 16);
  _Float16* Wt9 = (_Float16*)alloc((size_t)9 * HID * HID * 2);
  float* e_atom = (float*)alloc((size_t)N * 4);
  int* bsum = (int*)alloc(1024);
  (void)ws_size;

  hipMemsetAsync(counts, 0, (size_t)(N + 1) * 4, stream);
  hipMemsetAsync(out, 0, (size_t)out_size * 4, stream);

  const int nb = (N + 1023) / 1024;
  build_table_k<<<3 * TBL, 128, 0, stream>>>(mlp1_w, mlp1_b, mlp2_w, mlp2_b, tab);
  pair_table_k<<<(3 * TBL * 64 + 255) / 256, 256, 0, stream>>>(tab, tab2);
  wtrans9_k<<<9, 256, 0, stream>>>(lin1_w, lin2_w, int_w, Wt9);
  emb_gather_k<<<(N * 32 + 255) / 256, 256, 0, stream>>>(z, emb, h, N);
  edge_prep_k<<<(E + 255) / 256, 256, 0, stream>>>(row, col, pos, tq, counts, E);
  scan1_k<<<nb, 256, 0, stream>>>(counts, bsum, N);
  scan2_k<<<1, 256, 0, stream>>>(bsum, starts, nb, N);
  scan3_k<<<nb, 256, 0, stream>>>(counts, bsum, starts, cursor, N);
  scatter_k<<<(E + 255) / 256, 256, 0, stream>>>(row, col, tq, cursor, payload, E);

  int gemm_grid = (N + 63) / 64;
  for (int l = 0; l < 3; l++) {
    const _Float16* W1t = Wt9 + (size_t)l * HID * HID;
    const _Float16* W2t = Wt9 + (size_t)(3 + l) * HID * HID;
    const _Float16* W3t = Wt9 + (size_t)(6 + l) * HID * HID;
    mfma_lin1_k<<<gemm_grid, 256, 0, stream>>>(h, W1t, x16, N);
    aggregate_k<<<(N + 3) / 4, 256, 0, stream>>>(starts, payload, x16,
                                                 tab2 + (size_t)l * TBL * 64, agg16, N);
    mfma_fused23_k<<<gemm_grid, 256, 0, stream>>>(agg16, W2t, lin2_b + (size_t)l * HID,
                                                  W3t, int_b + (size_t)l * HID, h, N);
  }
  atom_energy_k<<<gemm_grid, 256, 0, stream>>>(h, out1_w, out1_b, out2_w, e_atom, N);
  seg_sum_k<<<(N + 255) / 256, 256, 0, stream>>>(e_atom, batch, out2_b, out, N);
}

// Round 5
// 679.413 us; speedup vs baseline: 2.2104x; 1.2498x over previous
//
#include <hip/hip_runtime.h>
#include <math.h>

#define HID 128
#define NGAUSS 50
#define TBL 2048
#define TBL2 8192
#define DMAX 8.6605f
#define LDX 136   // fp16 row pitch for MFMA LDS tiles (pad 8 halves)

typedef _Float16 h2 __attribute__((ext_vector_type(2)));
typedef _Float16 h4v __attribute__((ext_vector_type(4)));
typedef _Float16 f16x8 __attribute__((ext_vector_type(8)));
typedef float f32x4 __attribute__((ext_vector_type(4)));

__device__ __forceinline__ float sspf(float x) {
  float ax = fabsf(x);
  return fmaxf(x, 0.0f) + log1pf(expf(-ax)) - 0.69314718055994530942f;
}

__device__ __forceinline__ void fma4(float4& a, float s, const float4& w) {
  a.x = fmaf(s, w.x, a.x);
  a.y = fmaf(s, w.y, a.y);
  a.z = fmaf(s, w.z, a.z);
  a.w = fmaf(s, w.w, a.w);
}

// ---- Build W(d) lookup table (fp32, coarse): tab[l][ti][j]
__global__ __launch_bounds__(128) void build_table_k(
    const float* __restrict__ w1, const float* __restrict__ b1,
    const float* __restrict__ w2, const float* __restrict__ b2,
    float* __restrict__ tab) {
  int l = blockIdx.x >> 11;
  int ti = blockIdx.x & (TBL - 1);
  int j = threadIdx.x;
  __shared__ float rbf[NGAUSS];
  __shared__ float v1[HID];
  const float step = DMAX / (float)(TBL - 1);
  float d = ti * step;
  if (j < NGAUSS) {
    const float gstep = 10.0f / 49.0f;
    const float gcoeff = -12.005f;
    float diff = d - j * gstep;
    rbf[j] = expf(gcoeff * diff * diff);
  }
  __syncthreads();
  float s = b1[l * HID + j];
  const float* w1p = w1 + l * NGAUSS * HID + j;
  for (int g = 0; g < NGAUSS; g++) s = fmaf(rbf[g], w1p[g * HID], s);
  v1[j] = sspf(s);
  __syncthreads();
  float s2 = b2[l * HID + j];
  const float* w2p = w2 + l * HID * HID + j;
  for (int k = 0; k < HID; k++) s2 = fmaf(v1[k], w2p[k * HID], s2);
  float C = 0.5f * (cosf(d * 0.3141592653589793f) + 1.0f);
  tab[((size_t)l * TBL + ti) * HID + j] = s2 * C;
}

// ---- upsample coarse fp32 lerp table -> fine fp16 nearest table [l][TBL2][HID]
__global__ __launch_bounds__(256) void upsample_k(
    const float* __restrict__ tab, _Float16* __restrict__ tabh) {
  int idx = blockIdx.x * 256 + threadIdx.x;
  if (idx >= 3 * TBL2 * HID) return;
  int ch = idx & 127;
  int i = (idx >> 7) & (TBL2 - 1);
  int l = idx >> 20;
  float t = (float)i * ((float)(TBL - 1) / (float)(TBL2 - 1));
  int i0 = min((int)t, TBL - 2);
  float f = t - (float)i0;
  const float* base = tab + ((size_t)l * TBL + i0) * HID + ch;
  tabh[idx] = (_Float16)fmaf(f, base[HID] - base[0], base[0]);
}

// ---- transpose+convert the 9 128x128 weight matrices to fp16 Wt[n][k]
__global__ __launch_bounds__(256) void wtrans9_k(
    const float* __restrict__ lin1, const float* __restrict__ lin2,
    const float* __restrict__ intw, _Float16* __restrict__ out) {
  int b = blockIdx.x;
  const float* src = (b < 3 ? lin1 : (b < 6 ? lin2 : intw)) + (size_t)(b % 3) * HID * HID;
  _Float16* dst = out + (size_t)b * HID * HID;
  __shared__ _Float16 tile[128 * 130];
  int t = threadIdx.x;
  for (int i = t; i < HID * HID; i += 256) tile[(i >> 7) * 130 + (i & 127)] = (_Float16)src[i];
  __syncthreads();
  for (int i = t; i < HID * HID; i += 256) dst[i] = tile[(i & 127) * 130 + (i >> 7)];
}

// ---- h = emb[z]
__global__ __launch_bounds__(256) void emb_gather_k(
    const int* __restrict__ z, const float* __restrict__ emb,
    float* __restrict__ h, int N) {
  int i4 = blockIdx.x * 256 + threadIdx.x;
  if (i4 >= N * 32) return;
  int a = i4 >> 5;
  ((float4*)h)[i4] = ((const float4*)emb)[z[a] * 32 + (i4 & 31)];
}

// ---- per-edge distance -> nearest fine-table index (13 bit) + target histogram
__global__ __launch_bounds__(256) void edge_prep_k(
    const int* __restrict__ row, const int* __restrict__ col,
    const float* __restrict__ pos, int* __restrict__ tq,
    int* __restrict__ counts, int E) {
  int e = blockIdx.x * 256 + threadIdx.x;
  if (e >= E) return;
  int r = row[e], c = col[e];
  float dx = pos[r * 3 + 0] - pos[c * 3 + 0];
  float dy = pos[r * 3 + 1] - pos[c * 3 + 1];
  float dz = pos[r * 3 + 2] - pos[c * 3 + 2];
  float d = sqrtf(dx * dx + dy * dy + dz * dz);
  const float inv2 = (float)(TBL2 - 1) / DMAX;
  int q = (int)(d * inv2 + 0.5f);
  tq[e] = min(q, TBL2 - 1);
  atomicAdd(&counts[c], 1);
}

// ---- 3-phase coalesced exclusive scan
__global__ __launch_bounds__(256) void scan1_k(
    const int* __restrict__ counts, int* __restrict__ bsum, int N) {
  __shared__ int red[256];
  int b = blockIdx.x, t = threadIdx.x;
  int s = 0;
#pragma unroll
  for (int j = 0; j < 4; j++) {
    int i = b * 1024 + j * 256 + t;
    if (i < N) s += counts[i];
  }
  red[t] = s;
  __syncthreads();
  for (int o = 128; o > 0; o >>= 1) {
    if (t < o) red[t] += red[t + o];
    __syncthreads();
  }
  if (t == 0) bsum[b] = red[0];
}

__global__ __launch_bounds__(256) void scan2_k(
    int* __restrict__ bsum, int* __restrict__ starts, int nb, int N) {
  __shared__ int sh[256];
  int t = threadIdx.x;
  sh[t] = (t < nb) ? bsum[t] : 0;
  __syncthreads();
  for (int o = 1; o < 256; o <<= 1) {
    int v = (t >= o) ? sh[t - o] : 0;
    __syncthreads();
    sh[t] += v;
    __syncthreads();
  }
  if (t < nb) bsum[t] = (t == 0) ? 0 : sh[t - 1];
  if (t == 0) starts[N] = sh[255];
}

__global__ __launch_bounds__(256) void scan3_k(
    const int* __restrict__ counts, const int* __restrict__ bsum,
    int* __restrict__ starts, int N) {
  __shared__ int sh[256];
  int b = blockIdx.x, t = threadIdx.x;
  int base = b * 1024 + t * 4;
  int c[4];
#pragma unroll
  for (int j = 0; j < 4; j++) c[j] = (base + j < N) ? counts[base + j] : 0;
  int tsum = c[0] + c[1] + c[2] + c[3];
  sh[t] = tsum;
  __syncthreads();
  for (int o = 1; o < 256; o <<= 1) {
    int v = (t >= o) ? sh[t - o] : 0;
    __syncthreads();
    sh[t] += v;
    __syncthreads();
  }
  int p = bsum[b] + ((t == 0) ? 0 : sh[t - 1]);
#pragma unroll
  for (int j = 0; j < 4; j++) {
    if (base + j < N) {
      starts[base + j] = p;
      p += c[j];
    }
  }
}

// ---- bucket cursors: bcur[j] = starts[j*256]
__global__ __launch_bounds__(256) void bucket_init_k(
    const int* __restrict__ starts, int* __restrict__ bcur, int N, int nbuck) {
  int j = blockIdx.x * 256 + threadIdx.x;
  if (j < nbuck) bcur[j] = starts[min(j * 256, N)];
}

// ---- level-1 scatter: group edges into col>>8 buckets (chunked, L2-local writes)
#define CHUNK 2048
__global__ __launch_bounds__(256) void scatterA_k(
    const int* __restrict__ row, const int* __restrict__ col,
    const int* __restrict__ tq, int* __restrict__ bcur,
    unsigned long long* __restrict__ tmp, int E, int nbuck) {
  __shared__ int hist[256];
  __shared__ int base[256];
  int t = threadIdx.x;
  int e0 = blockIdx.x * CHUNK;
  for (int j = t; j < nbuck; j += 256) hist[j] = 0;
  __syncthreads();
  int bkt[8];
  int rnk[8];
  unsigned long long key[8];
#pragma unroll
  for (int u = 0; u < 8; u++) {
    int e = e0 + u * 256 + t;
    bkt[u] = -1;
    if (e < E) {
      int c = col[e];
      unsigned int pay = ((unsigned int)row[e] << 13) | (unsigned int)tq[e];
      key[u] = ((unsigned long long)pay << 8) | (unsigned long long)(c & 255);
      bkt[u] = c >> 8;
      rnk[u] = atomicAdd(&hist[bkt[u]], 1);
    }
  }
  __syncthreads();
  for (int j = t; j < nbuck; j += 256)
    base[j] = hist[j] ? atomicAdd(&bcur[j], hist[j]) : 0;
  __syncthreads();
#pragma unroll
  for (int u = 0; u < 8; u++)
    if (bkt[u] >= 0) tmp[(size_t)base[bkt[u]] + rnk[u]] = key[u];
}

// ---- level-2 scatter: one block per bucket, LDS cursors, 32KB-local writes
__global__ __launch_bounds__(256) void scatterB_k(
    const unsigned long long* __restrict__ tmp, const int* __restrict__ starts,
    unsigned int* __restrict__ payload, int N) {
  int j = blockIdx.x;
  int t = threadIdx.x;
  __shared__ int cur[256];
  int c0 = j * 256;
  int c = c0 + t;
  cur[t] = (c < N) ? starts[c] : 0;
  int rs = starts[min(c0, N)];
  int re = starts[min(c0 + 256, N)];
  __syncthreads();
  for (int e = rs + t; e < re; e += 256) {
    unsigned long long k = tmp[e];
    int cl = (int)(k & 255);
    unsigned int pay = (unsigned int)(k >> 8);
    int p = atomicAdd(&cur[cl], 1);
    payload[p] = pay;
  }
}

// ---- MFMA GEMM: x16[a][:] = (fp16)(h[a][:] @ W)   W pre-transposed fp16 Wt[n][k]
__global__ __launch_bounds__(256) void mfma_lin1_k(
    const float* __restrict__ in, const _Float16* __restrict__ Wt,
    _Float16* __restrict__ x16, int N) {
  __shared__ __align__(16) _Float16 Xs[64 * LDX];
  __shared__ __align__(16) _Float16 Ws[128 * LDX];
  int t = threadIdx.x;
  int a0 = blockIdx.x * 64;
#pragma unroll
  for (int p = 0; p < 8; p++) {
    int fi = t + p * 256;
    int a = fi >> 5, kg = fi & 31;
    float4 v = make_float4(0.f, 0.f, 0.f, 0.f);
    if (a0 + a < N) v = ((const float4*)in)[(size_t)(a0 + a) * 32 + kg];
    h4v o;
    o.x = (_Float16)v.x; o.y = (_Float16)v.y;
    o.z = (_Float16)v.z; o.w = (_Float16)v.w;
    *(h4v*)&Xs[a * LDX + kg * 4] = o;
  }
#pragma unroll
  for (int p = 0; p < 8; p++) {
    int si = t + p * 256;
    int n = si >> 4, kg = si & 15;
    *(uint4*)&Ws[n * LDX + kg * 8] = ((const uint4*)Wt)[si];
  }
  __syncthreads();
  int lane = t & 63;
  int w = t >> 6;
  int mrow = lane & 15, quad = lane >> 4;
  f32x4 zero = {0.f, 0.f, 0.f, 0.f};
  f32x4 acc[8];
#pragma unroll
  for (int i = 0; i < 8; i++) acc[i] = zero;
#pragma unroll
  for (int kk = 0; kk < 4; kk++) {
    f16x8 af = *(const f16x8*)&Xs[(w * 16 + mrow) * LDX + kk * 32 + quad * 8];
#pragma unroll
    for (int nt = 0; nt < 8; nt++) {
      f16x8 bf = *(const f16x8*)&Ws[(nt * 16 + mrow) * LDX + kk * 32 + quad * 8];
      acc[nt] = __builtin_amdgcn_mfma_f32_16x16x32_f16(af, bf, acc[nt], 0, 0, 0);
    }
  }
  __syncthreads();
#pragma unroll
  for (int nt = 0; nt < 8; nt++)
#pragma unroll
    for (int r = 0; r < 4; r++)
      Xs[(w * 16 + quad * 4 + r) * LDX + nt * 16 + mrow] = (_Float16)acc[nt][r];
  __syncthreads();
#pragma unroll
  for (int p = 0; p < 4; p++) {
    int ci = t + p * 256;
    int a = ci >> 4, kg = ci & 15;
    if (a0 + a < N)
      ((uint4*)x16)[(size_t)(a0 + a) * 16 + kg] = *(uint4*)&Xs[a * LDX + kg * 8];
  }
}

// ---- MFMA fused: h += ssp(agg16 @ W2 + b2) @ W3 + b3
__global__ __launch_bounds__(256) void mfma_fused23_k(
    const _Float16* __restrict__ agg16, const _Float16* __restrict__ W2t,
    const float* __restrict__ b2, const _Float16* __restrict__ W3t,
    const float* __restrict__ b3, float* __restrict__ h, int N) {
  __shared__ __align__(16) _Float16 Xs[64 * LDX];
  __shared__ __align__(16) _Float16 Ws[128 * LDX];
  int t = threadIdx.x;
  int a0 = blockIdx.x * 64;
#pragma unroll
  for (int p = 0; p < 4; p++) {
    int ci = t + p * 256;
    int a = ci >> 4, kg = ci & 15;
    uint4 v = make_uint4(0, 0, 0, 0);
    if (a0 + a < N) v = ((const uint4*)agg16)[(size_t)(a0 + a) * 16 + kg];
    *(uint4*)&Xs[a * LDX + kg * 8] = v;
  }
#pragma unroll
  for (int p = 0; p < 8; p++) {
    int si = t + p * 256;
    int n = si >> 4, kg = si & 15;
    *(uint4*)&Ws[n * LDX + kg * 8] = ((const uint4*)W2t)[si];
  }
  __syncthreads();
  int lane = t & 63;
  int w = t >> 6;
  int mrow = lane & 15, quad = lane >> 4;
  f32x4 zero = {0.f, 0.f, 0.f, 0.f};
  f32x4 acc[8];
#pragma unroll
  for (int i = 0; i < 8; i++) acc[i] = zero;
#pragma unroll
  for (int kk = 0; kk < 4; kk++) {
    f16x8 af = *(const f16x8*)&Xs[(w * 16 + mrow) * LDX + kk * 32 + quad * 8];
#pragma unroll
    for (int nt = 0; nt < 8; nt++) {
      f16x8 bf = *(const f16x8*)&Ws[(nt * 16 + mrow) * LDX + kk * 32 + quad * 8];
      acc[nt] = __builtin_amdgcn_mfma_f32_16x16x32_f16(af, bf, acc[nt], 0, 0, 0);
    }
  }
  float b2r[8];
#pragma unroll
  for (int nt = 0; nt < 8; nt++) b2r[nt] = b2[nt * 16 + mrow];
  __syncthreads();
#pragma unroll
  for (int nt = 0; nt < 8; nt++)
#pragma unroll
    for (int r = 0; r < 4; r++)
      Xs[(w * 16 + quad * 4 + r) * LDX + nt * 16 + mrow] = (_Float16)sspf(acc[nt][r] + b2r[nt]);
#pragma unroll
  for (int p = 0; p < 8; p++) {
    int si = t + p * 256;
    int n = si >> 4, kg = si & 15;
    *(uint4*)&Ws[n * LDX + kg * 8] = ((const uint4*)W3t)[si];
  }
  __syncthreads();
#pragma unroll
  for (int i = 0; i < 8; i++) acc[i] = zero;
#pragma unroll
  for (int kk = 0; kk < 4; kk++) {
    f16x8 af = *(const f16x8*)&Xs[(w * 16 + mrow) * LDX + kk * 32 + quad * 8];
#pragma unroll
    for (int nt = 0; nt < 8; nt++) {
      f16x8 bf = *(const f16x8*)&Ws[(nt * 16 + mrow) * LDX + kk * 32 + quad * 8];
      acc[nt] = __builtin_amdgcn_mfma_f32_16x16x32_f16(af, bf, acc[nt], 0, 0, 0);
    }
  }
  float b3r[8];
#pragma unroll
  for (int nt = 0; nt < 8; nt++) b3r[nt] = b3[nt * 16 + mrow];
#pragma unroll
  for (int nt = 0; nt < 8; nt++)
#pragma unroll
    for (int r = 0; r < 4; r++) {
      int a = a0 + w * 16 + quad * 4 + r;
      if (a < N) {
        size_t idx = (size_t)a * HID + nt * 16 + mrow;
        h[idx] += acc[nt][r] + b3r[nt];
      }
    }
}

// ---- agg16[a] = (fp16) sum_{e: col=a} x16[row_e] * tabh[tq_e]  (nearest lookup)
__global__ __launch_bounds__(256) void aggregate_k(
    const int* __restrict__ starts, const unsigned int* __restrict__ payload,
    const _Float16* __restrict__ x16, const _Float16* __restrict__ tabh,
    _Float16* __restrict__ agg16, int N) {
  int a = blockIdx.x * 4 + (threadIdx.x >> 6);
  if (a >= N) return;
  int lane = threadIdx.x & 63;
  int s = starts[a], e_end = starts[a + 1];
  float2 acc = make_float2(0.f, 0.f);
  const h2* xv = (const h2*)x16;
  const h2* tv = (const h2*)tabh;
  auto do_edge = [&](unsigned int p) {
    int i0 = (int)(p & 8191u);
    int r = (int)(p >> 13);
    h2 wv = tv[(size_t)i0 * 64 + lane];
    h2 xr = xv[(size_t)r * 64 + lane];
    acc.x = fmaf((float)xr.x, (float)wv.x, acc.x);
    acc.y = fmaf((float)xr.y, (float)wv.y, acc.y);
  };
  int i = s;
  while ((i & 3) && i < e_end) { do_edge(payload[i]); i++; }
  const uint4* pp = (const uint4*)payload;
  for (; i + 8 <= e_end; i += 8) {
    uint4 q0 = pp[i >> 2];
    uint4 q1 = pp[(i >> 2) + 1];
    do_edge(q0.x); do_edge(q0.y); do_edge(q0.z); do_edge(q0.w);
    do_edge(q1.x); do_edge(q1.y); do_edge(q1.z); do_edge(q1.w);
  }
  for (; i < e_end; i++) do_edge(payload[i]);
  h2 o; o.x = (_Float16)acc.x; o.y = (_Float16)acc.y;
  ((h2*)agg16)[(size_t)a * 64 + lane] = o;
}

// ---- per-atom energy: e[a] = ssp(h[a]@o1w + o1b) . o2w
__global__ __launch_bounds__(256) void atom_energy_k(
    const float* __restrict__ h, const float* __restrict__ o1w,
    const float* __restrict__ o1b, const float* __restrict__ o2w,
    float* __restrict__ e, int N) {
  __shared__ float xs[64 * HID];
  int t = threadIdx.x;
  int a0 = blockIdx.x * 64;
#pragma unroll
  for (int p = 0; p < 8; p++) {
    int fi = t + p * 256;
    int a = a0 + (fi >> 5);
    float4 v = make_float4(0.f, 0.f, 0.f, 0.f);
    if (a < N) v = ((const float4*)h)[(size_t)a * 32 + (fi & 31)];
    ((float4*)xs)[fi] = v;
  }
  __syncthreads();
  int jg = t & 15;
  int ar = t >> 4;
  float4 acc[4];
#pragma unroll
  for (int i = 0; i < 4; i++) acc[i] = make_float4(0.f, 0.f, 0.f, 0.f);
  const float4* Wv = (const float4*)o1w;
  for (int k = 0; k < HID; k += 4) {
    float4 w0 = Wv[(k + 0) * 16 + jg];
    float4 w1 = Wv[(k + 1) * 16 + jg];
    float4 w2 = Wv[(k + 2) * 16 + jg];
    float4 w3 = Wv[(k + 3) * 16 + jg];
#pragma unroll
    for (int i = 0; i < 4; i++) {
      float4 xv = *(const float4*)&xs[(ar * 4 + i) * HID + k];
      float4 a4 = acc[i];
      fma4(a4, xv.x, w0);
      fma4(a4, xv.y, w1);
      fma4(a4, xv.z, w2);
      fma4(a4, xv.w, w3);
      acc[i] = a4;
    }
  }
  float4 b = ((const float4*)o1b)[jg];
  float4 ow = ((const float4*)o2w)[jg];
#pragma unroll
  for (int i = 0; i < 4; i++) {
    float4 v = acc[i];
    float y = sspf(v.x + b.x) * ow.x + sspf(v.y + b.y) * ow.y +
              sspf(v.z + b.z) * ow.z + sspf(v.w + b.w) * ow.w;
    y += __shfl_xor(y, 1);
    y += __shfl_xor(y, 2);
    y += __shfl_xor(y, 4);
    y += __shfl_xor(y, 8);
    int a = a0 + ar * 4 + i;
    if (jg == 0 && a < N) e[a] = y;
  }
}

__global__ __launch_bounds__(256) void seg_sum_k(
    const float* __restrict__ e, const int* __restrict__ batch,
    const float* __restrict__ o2b, float* __restrict__ out, int N) {
  int a = blockIdx.x * 256 + threadIdx.x;
  if (a >= N) return;
  atomicAdd(&out[batch[a]], e[a] + o2b[0]);
}

extern "C" void kernel_launch(void* const* d_in, const int* in_sizes, int n_in,
                              void* d_out, int out_size, void* d_ws, size_t ws_size,
                              hipStream_t stream) {
  const int* z = (const int*)d_in[0];
  const float* pos = (const float*)d_in[1];
  const int* batch = (const int*)d_in[2];
  const int* eidx = (const int*)d_in[3];
  const float* emb = (const float*)d_in[4];
  const float* mlp1_w = (const float*)d_in[5];
  const float* mlp1_b = (const float*)d_in[6];
  const float* mlp2_w = (const float*)d_in[7];
  const float* mlp2_b = (const float*)d_in[8];
  const float* lin1_w = (const float*)d_in[9];
  const float* lin2_w = (const float*)d_in[10];
  const float* lin2_b = (const float*)d_in[11];
  const float* int_w = (const float*)d_in[12];
  const float* int_b = (const float*)d_in[13];
  const float* out1_w = (const float*)d_in[14];
  const float* out1_b = (const float*)d_in[15];
  const float* out2_w = (const float*)d_in[16];
  const float* out2_b = (const float*)d_in[17];
  float* out = (float*)d_out;

  const int N = in_sizes[0];
  const int E = in_sizes[3] / 2;
  const int* row = eidx;
  const int* col = eidx + E;
  const int nbuck = (N + 255) / 256;

  char* ws = (char*)d_ws;
  size_t off = 0;
  auto alloc = [&](size_t bytes) -> void* {
    void* p = ws + off;
    off = (off + bytes + 255) & ~(size_t)255;
    return p;
  };
  float* h = (float*)alloc((size_t)N * HID * 4);
  _Float16* x16 = (_Float16*)alloc((size_t)N * HID * 2);
  // tmp (uint64/edge, scatter staging) aliases agg16 (dead until after scatterB)
  size_t agg_bytes = (size_t)N * HID * 2;
  size_t tmp_bytes = (size_t)E * 8 + 16;
  void* agg_union = alloc(agg_bytes > tmp_bytes ? agg_bytes : tmp_bytes);
  _Float16* agg16 = (_Float16*)agg_union;
  unsigned long long* tmp = (unsigned long long*)agg_union;
  int* tq = (int*)alloc((size_t)E * 4);
  unsigned int* payload = (unsigned int*)alloc((size_t)E * 4 + 16);
  int* counts = (int*)alloc((size_t)(N + 1) * 4);
  int* starts = (int*)alloc((size_t)(N + 1) * 4);
  int* bcur = (int*)alloc((size_t)nbuck * 4);
  float* tab = (float*)alloc((size_t)3 * TBL * HID * 4);
  _Float16* tabh = (_Float16*)alloc((size_t)3 * TBL2 * HID * 2);
  _Float16* Wt9 = (_Float16*)alloc((size_t)9 * HID * HID * 2);
  float* e_atom = (float*)alloc((size_t)N * 4);
  int* bsum = (int*)alloc(1024);
  (void)ws_size;

  hipMemsetAsync(counts, 0, (size_t)(N + 1) * 4, stream);
  hipMemsetAsync(out, 0, (size_t)out_size * 4, stream);

  const int nb = (N + 1023) / 1024;
  build_table_k<<<3 * TBL, 128, 0, stream>>>(mlp1_w, mlp1_b, mlp2_w, mlp2_b, tab);
  upsample_k<<<(3 * TBL2 * HID + 255) / 256, 256, 0, stream>>>(tab, tabh);
  wtrans9_k<<<9, 256, 0, stream>>>(lin1_w, lin2_w, int_w, Wt9);
  emb_gather_k<<<(N * 32 + 255) / 256, 256, 0, stream>>>(z, emb, h, N);
  edge_prep_k<<<(E + 255) / 256, 256, 0, stream>>>(row, col, pos, tq, counts, E);
  scan1_k<<<nb, 256, 0, stream>>>(counts, bsum, N);
  scan2_k<<<1, 256, 0, stream>>>(bsum, starts, nb, N);
  scan3_k<<<nb, 256, 0, stream>>>(counts, bsum, starts, N);
  bucket_init_k<<<(nbuck + 255) / 256, 256, 0, stream>>>(starts, bcur, N, nbuck);
  scatterA_k<<<(E + CHUNK - 1) / CHUNK, 256, 0, stream>>>(row, col, tq, bcur, tmp, E, nbuck);
  scatterB_k<<<nbuck, 256, 0, stream>>>(tmp, starts, payload, N);

  int gemm_grid = (N + 63) / 64;
  for (int l = 0; l < 3; l++) {
    const _Float16* W1t = Wt9 + (size_t)l * HID * HID;
    const _Float16* W2t = Wt9 + (size_t)(3 + l) * HID * HID;
    const _Float16* W3t = Wt9 + (size_t)(6 + l) * HID * HID;
    mfma_lin1_k<<<gemm_grid, 256, 0, stream>>>(h, W1t, x16, N);
    aggregate_k<<<(N + 3) / 4, 256, 0, stream>>>(starts, payload, x16,
                                                 tabh + (size_t)l * TBL2 * HID, agg16, N);
    mfma_fused23_k<<<gemm_grid, 256, 0, stream>>>(agg16, W2t, lin2_b + (size_t)l * HID,
                                                  W3t, int_b + (size_t)l * HID, h, N);
  }
  atom_energy_k<<<gemm_grid, 256, 0, stream>>>(h, out1_w, out1_b, out2_w, e_atom, N);
  seg_sum_k<<<(N + 255) / 256, 256, 0, stream>>>(e_atom, batch, out2_b, out, N);
}

// Round 6
// 638.184 us; speedup vs baseline: 2.3532x; 1.0646x over previous
//
#include <hip/hip_runtime.h>
#include <math.h>

#define HID 128
#define NGAUSS 50
#define TBL 2048
#define TBL2 8192
#define DMAX 8.6605f
#define LDX 136   // fp16 row pitch for MFMA LDS tiles (pad 8 halves)

typedef _Float16 h2 __attribute__((ext_vector_type(2)));
typedef _Float16 h4 __attribute__((ext_vector_type(4)));
typedef _Float16 f16x8 __attribute__((ext_vector_type(8)));
typedef float f32x4 __attribute__((ext_vector_type(4)));

__device__ __forceinline__ float sspf(float x) {
  float ax = fabsf(x);
  return fmaxf(x, 0.0f) + log1pf(expf(-ax)) - 0.69314718055994530942f;
}

__device__ __forceinline__ void fma4(float4& a, float s, const float4& w) {
  a.x = fmaf(s, w.x, a.x);
  a.y = fmaf(s, w.y, a.y);
  a.z = fmaf(s, w.z, a.z);
  a.w = fmaf(s, w.w, a.w);
}

// ---- Build W(d) lookup table (fp32, coarse): tab[l][ti][j]
__global__ __launch_bounds__(128) void build_table_k(
    const float* __restrict__ w1, const float* __restrict__ b1,
    const float* __restrict__ w2, const float* __restrict__ b2,
    float* __restrict__ tab) {
  int l = blockIdx.x >> 11;
  int ti = blockIdx.x & (TBL - 1);
  int j = threadIdx.x;
  __shared__ float rbf[NGAUSS];
  __shared__ float v1[HID];
  const float step = DMAX / (float)(TBL - 1);
  float d = ti * step;
  if (j < NGAUSS) {
    const float gstep = 10.0f / 49.0f;
    const float gcoeff = -12.005f;
    float diff = d - j * gstep;
    rbf[j] = expf(gcoeff * diff * diff);
  }
  __syncthreads();
  float s = b1[l * HID + j];
  const float* w1p = w1 + l * NGAUSS * HID + j;
  for (int g = 0; g < NGAUSS; g++) s = fmaf(rbf[g], w1p[g * HID], s);
  v1[j] = sspf(s);
  __syncthreads();
  float s2 = b2[l * HID + j];
  const float* w2p = w2 + l * HID * HID + j;
  for (int k = 0; k < HID; k++) s2 = fmaf(v1[k], w2p[k * HID], s2);
  float C = 0.5f * (cosf(d * 0.3141592653589793f) + 1.0f);
  tab[((size_t)l * TBL + ti) * HID + j] = s2 * C;
}

// ---- upsample coarse fp32 lerp table -> fine fp16 nearest table [l][TBL2][HID]
__global__ __launch_bounds__(256) void upsample_k(
    const float* __restrict__ tab, _Float16* __restrict__ tabh) {
  int idx = blockIdx.x * 256 + threadIdx.x;
  if (idx >= 3 * TBL2 * HID) return;
  int ch = idx & 127;
  int i = (idx >> 7) & (TBL2 - 1);
  int l = idx >> 20;
  float t = (float)i * ((float)(TBL - 1) / (float)(TBL2 - 1));
  int i0 = min((int)t, TBL - 2);
  float f = t - (float)i0;
  const float* base = tab + ((size_t)l * TBL + i0) * HID + ch;
  tabh[idx] = (_Float16)fmaf(f, base[HID] - base[0], base[0]);
}

// ---- transpose+convert the 9 128x128 weight matrices to fp16 Wt[n][k]
__global__ __launch_bounds__(256) void wtrans9_k(
    const float* __restrict__ lin1, const float* __restrict__ lin2,
    const float* __restrict__ intw, _Float16* __restrict__ out) {
  int b = blockIdx.x;
  const float* src = (b < 3 ? lin1 : (b < 6 ? lin2 : intw)) + (size_t)(b % 3) * HID * HID;
  _Float16* dst = out + (size_t)b * HID * HID;
  __shared__ _Float16 tile[128 * 130];
  int t = threadIdx.x;
  for (int i = t; i < HID * HID; i += 256) tile[(i >> 7) * 130 + (i & 127)] = (_Float16)src[i];
  __syncthreads();
  for (int i = t; i < HID * HID; i += 256) dst[i] = tile[(i & 127) * 130 + (i >> 7)];
}

// ---- h = emb[z]
__global__ __launch_bounds__(256) void emb_gather_k(
    const int* __restrict__ z, const float* __restrict__ emb,
    float* __restrict__ h, int N) {
  int i4 = blockIdx.x * 256 + threadIdx.x;
  if (i4 >= N * 32) return;
  int a = i4 >> 5;
  ((float4*)h)[i4] = ((const float4*)emb)[z[a] * 32 + (i4 & 31)];
}

// ---- per-edge distance -> table index; coarse-bucket histogram (LDS, aggregated)
__global__ __launch_bounds__(256) void edge_prep_k(
    const int* __restrict__ row, const int* __restrict__ col,
    const float* __restrict__ pos, int* __restrict__ tq,
    int* __restrict__ bcount, int E, int nbuck) {
  __shared__ int hist[1024];
  int t = threadIdx.x;
  int e0 = blockIdx.x * 2048;
  for (int j = t; j < nbuck; j += 256) hist[j] = 0;
  __syncthreads();
#pragma unroll
  for (int u = 0; u < 8; u++) {
    int e = e0 + u * 256 + t;
    if (e < E) {
      int r = row[e], c = col[e];
      float dx = pos[r * 3 + 0] - pos[c * 3 + 0];
      float dy = pos[r * 3 + 1] - pos[c * 3 + 1];
      float dz = pos[r * 3 + 2] - pos[c * 3 + 2];
      float d = sqrtf(dx * dx + dy * dy + dz * dz);
      const float inv2 = (float)(TBL2 - 1) / DMAX;
      int q = (int)(d * inv2 + 0.5f);
      tq[e] = min(q, TBL2 - 1);
      atomicAdd(&hist[c >> 6], 1);
    }
  }
  __syncthreads();
  for (int j = t; j < nbuck; j += 256)
    if (hist[j]) atomicAdd(&bcount[j], hist[j]);
}

// ---- exclusive scan of bucket counts (single block)
__global__ __launch_bounds__(256) void bucket_scan_k(
    const int* __restrict__ bcount, int* __restrict__ bstart,
    int* __restrict__ bcur, int nbuck, int* __restrict__ starts, int N) {
  __shared__ int sh[256];
  int t = threadIdx.x;
  int chunk = (nbuck + 255) / 256;   // <= 8
  int b0 = t * chunk;
  int c[8];
  int s = 0;
  for (int j = 0; j < chunk; j++) {
    int idx = b0 + j;
    int v = (idx < nbuck) ? bcount[idx] : 0;
    c[j] = v;
    s += v;
  }
  sh[t] = s;
  __syncthreads();
  for (int o = 1; o < 256; o <<= 1) {
    int v = (t >= o) ? sh[t - o] : 0;
    __syncthreads();
    sh[t] += v;
    __syncthreads();
  }
  int p = (t == 0) ? 0 : sh[t - 1];
  for (int j = 0; j < chunk; j++) {
    int idx = b0 + j;
    if (idx < nbuck) {
      bstart[idx] = p;
      bcur[idx] = p;
      p += c[j];
    }
  }
  if (t == 255) {
    bstart[nbuck] = p;
    starts[N] = p;
  }
}

// ---- level-1 scatter into 64-atom buckets (chunk-contiguous writes)
__global__ __launch_bounds__(256) void scatterA_k(
    const int* __restrict__ row, const int* __restrict__ col,
    const int* __restrict__ tq, int* __restrict__ bcur,
    unsigned long long* __restrict__ tmp, int E, int nbuck) {
  __shared__ int hist[1024];
  __shared__ int base[1024];
  int t = threadIdx.x;
  int e0 = blockIdx.x * 2048;
  for (int j = t; j < nbuck; j += 256) hist[j] = 0;
  __syncthreads();
  int bkt[8];
  int rnk[8];
  unsigned long long key[8];
#pragma unroll
  for (int u = 0; u < 8; u++) {
    int e = e0 + u * 256 + t;
    bkt[u] = -1;
    if (e < E) {
      int c = col[e];
      unsigned int pay = ((unsigned int)row[e] << 13) | (unsigned int)tq[e];
      key[u] = ((unsigned long long)pay << 6) | (unsigned long long)(c & 63);
      bkt[u] = c >> 6;
      rnk[u] = atomicAdd(&hist[bkt[u]], 1);
    }
  }
  __syncthreads();
  for (int j = t; j < nbuck; j += 256)
    base[j] = hist[j] ? atomicAdd(&bcur[j], hist[j]) : 0;
  __syncthreads();
#pragma unroll
  for (int u = 0; u < 8; u++)
    if (bkt[u] >= 0) tmp[(size_t)base[bkt[u]] + rnk[u]] = key[u];
}

// ---- level-2: per-bucket per-atom counts (LDS) -> starts, then local scatter
__global__ __launch_bounds__(256) void scatterB_k(
    const unsigned long long* __restrict__ tmp, const int* __restrict__ bstart,
    int* __restrict__ starts, unsigned int* __restrict__ payload, int N) {
  int j = blockIdx.x;
  int t = threadIdx.x;
  __shared__ int cnt[64];
  __shared__ int cur[64];
  int rs = bstart[j], re = bstart[j + 1];
  if (t < 64) cnt[t] = 0;
  __syncthreads();
  for (int e = rs + t; e < re; e += 256)
    atomicAdd(&cnt[(int)(tmp[e] & 63)], 1);
  __syncthreads();
  if (t < 64) {
    int mine = cnt[t];
    int v = mine;
    for (int o = 1; o < 64; o <<= 1) {
      int u = __shfl_up(v, o, 64);
      if (t >= o) v += u;
    }
    int excl = v - mine;
    int c = j * 64 + t;
    if (c < N) starts[c] = rs + excl;
    cur[t] = rs + excl;
  }
  __syncthreads();
  for (int e = rs + t; e < re; e += 256) {
    unsigned long long k = tmp[e];
    int p = atomicAdd(&cur[(int)(k & 63)], 1);
    payload[p] = (unsigned int)(k >> 6);
  }
}

// ---- MFMA GEMM: x16[a][:] = (fp16)(h[a][:] @ W)   W pre-transposed fp16 Wt[n][k]
__global__ __launch_bounds__(256) void mfma_lin1_k(
    const float* __restrict__ in, const _Float16* __restrict__ Wt,
    _Float16* __restrict__ x16, int N) {
  __shared__ __align__(16) _Float16 Xs[64 * LDX];
  __shared__ __align__(16) _Float16 Ws[128 * LDX];
  int t = threadIdx.x;
  int a0 = blockIdx.x * 64;
#pragma unroll
  for (int p = 0; p < 8; p++) {
    int fi = t + p * 256;
    int a = fi >> 5, kg = fi & 31;
    float4 v = make_float4(0.f, 0.f, 0.f, 0.f);
    if (a0 + a < N) v = ((const float4*)in)[(size_t)(a0 + a) * 32 + kg];
    h4 o;
    o.x = (_Float16)v.x; o.y = (_Float16)v.y;
    o.z = (_Float16)v.z; o.w = (_Float16)v.w;
    *(h4*)&Xs[a * LDX + kg * 4] = o;
  }
#pragma unroll
  for (int p = 0; p < 8; p++) {
    int si = t + p * 256;
    int n = si >> 4, kg = si & 15;
    *(uint4*)&Ws[n * LDX + kg * 8] = ((const uint4*)Wt)[si];
  }
  __syncthreads();
  int lane = t & 63;
  int w = t >> 6;
  int mrow = lane & 15, quad = lane >> 4;
  f32x4 zero = {0.f, 0.f, 0.f, 0.f};
  f32x4 acc[8];
#pragma unroll
  for (int i = 0; i < 8; i++) acc[i] = zero;
#pragma unroll
  for (int kk = 0; kk < 4; kk++) {
    f16x8 af = *(const f16x8*)&Xs[(w * 16 + mrow) * LDX + kk * 32 + quad * 8];
#pragma unroll
    for (int nt = 0; nt < 8; nt++) {
      f16x8 bf = *(const f16x8*)&Ws[(nt * 16 + mrow) * LDX + kk * 32 + quad * 8];
      acc[nt] = __builtin_amdgcn_mfma_f32_16x16x32_f16(af, bf, acc[nt], 0, 0, 0);
    }
  }
  __syncthreads();
#pragma unroll
  for (int nt = 0; nt < 8; nt++)
#pragma unroll
    for (int r = 0; r < 4; r++)
      Xs[(w * 16 + quad * 4 + r) * LDX + nt * 16 + mrow] = (_Float16)acc[nt][r];
  __syncthreads();
#pragma unroll
  for (int p = 0; p < 4; p++) {
    int ci = t + p * 256;
    int a = ci >> 4, kg = ci & 15;
    if (a0 + a < N)
      ((uint4*)x16)[(size_t)(a0 + a) * 16 + kg] = *(uint4*)&Xs[a * LDX + kg * 8];
  }
}

// ---- MFMA fused: h += ssp(agg16 @ W2 + b2) @ W3 + b3
__global__ __launch_bounds__(256) void mfma_fused23_k(
    const _Float16* __restrict__ agg16, const _Float16* __restrict__ W2t,
    const float* __restrict__ b2, const _Float16* __restrict__ W3t,
    const float* __restrict__ b3, float* __restrict__ h, int N) {
  __shared__ __align__(16) _Float16 Xs[64 * LDX];
  __shared__ __align__(16) _Float16 Ws[128 * LDX];
  int t = threadIdx.x;
  int a0 = blockIdx.x * 64;
#pragma unroll
  for (int p = 0; p < 4; p++) {
    int ci = t + p * 256;
    int a = ci >> 4, kg = ci & 15;
    uint4 v = make_uint4(0, 0, 0, 0);
    if (a0 + a < N) v = ((const uint4*)agg16)[(size_t)(a0 + a) * 16 + kg];
    *(uint4*)&Xs[a * LDX + kg * 8] = v;
  }
#pragma unroll
  for (int p = 0; p < 8; p++) {
    int si = t + p * 256;
    int n = si >> 4, kg = si & 15;
    *(uint4*)&Ws[n * LDX + kg * 8] = ((const uint4*)W2t)[si];
  }
  __syncthreads();
  int lane = t & 63;
  int w = t >> 6;
  int mrow = lane & 15, quad = lane >> 4;
  f32x4 zero = {0.f, 0.f, 0.f, 0.f};
  f32x4 acc[8];
#pragma unroll
  for (int i = 0; i < 8; i++) acc[i] = zero;
#pragma unroll
  for (int kk = 0; kk < 4; kk++) {
    f16x8 af = *(const f16x8*)&Xs[(w * 16 + mrow) * LDX + kk * 32 + quad * 8];
#pragma unroll
    for (int nt = 0; nt < 8; nt++) {
      f16x8 bf = *(const f16x8*)&Ws[(nt * 16 + mrow) * LDX + kk * 32 + quad * 8];
      acc[nt] = __builtin_amdgcn_mfma_f32_16x16x32_f16(af, bf, acc[nt], 0, 0, 0);
    }
  }
  float b2r[8];
#pragma unroll
  for (int nt = 0; nt < 8; nt++) b2r[nt] = b2[nt * 16 + mrow];
  __syncthreads();
#pragma unroll
  for (int nt = 0; nt < 8; nt++)
#pragma unroll
    for (int r = 0; r < 4; r++)
      Xs[(w * 16 + quad * 4 + r) * LDX + nt * 16 + mrow] = (_Float16)sspf(acc[nt][r] + b2r[nt]);
#pragma unroll
  for (int p = 0; p < 8; p++) {
    int si = t + p * 256;
    int n = si >> 4, kg = si & 15;
    *(uint4*)&Ws[n * LDX + kg * 8] = ((const uint4*)W3t)[si];
  }
  __syncthreads();
#pragma unroll
  for (int i = 0; i < 8; i++) acc[i] = zero;
#pragma unroll
  for (int kk = 0; kk < 4; kk++) {
    f16x8 af = *(const f16x8*)&Xs[(w * 16 + mrow) * LDX + kk * 32 + quad * 8];
#pragma unroll
    for (int nt = 0; nt < 8; nt++) {
      f16x8 bf = *(const f16x8*)&Ws[(nt * 16 + mrow) * LDX + kk * 32 + quad * 8];
      acc[nt] = __builtin_amdgcn_mfma_f32_16x16x32_f16(af, bf, acc[nt], 0, 0, 0);
    }
  }
  float b3r[8];
#pragma unroll
  for (int nt = 0; nt < 8; nt++) b3r[nt] = b3[nt * 16 + mrow];
#pragma unroll
  for (int nt = 0; nt < 8; nt++)
#pragma unroll
    for (int r = 0; r < 4; r++) {
      int a = a0 + w * 16 + quad * 4 + r;
      if (a < N) {
        size_t idx = (size_t)a * HID + nt * 16 + mrow;
        h[idx] += acc[nt][r] + b3r[nt];
      }
    }
}

// ---- agg16[a] = (fp16) sum_{e: col=a} x16[row_e] * tabh[tq_e]
// 2 edges per wave (32 lanes x 8B each), cross-half shfl reduce
__global__ __launch_bounds__(256) void aggregate_k(
    const int* __restrict__ starts, const unsigned int* __restrict__ payload,
    const _Float16* __restrict__ x16, const _Float16* __restrict__ tabh,
    _Float16* __restrict__ agg16, int N) {
  int a = blockIdx.x * 4 + (threadIdx.x >> 6);
  if (a >= N) return;
  int lane = threadIdx.x & 63;
  int half = lane >> 5;
  int sl = lane & 31;          // channels 4*sl .. 4*sl+3
  int s = starts[a], e_end = starts[a + 1];
  float4 acc0 = make_float4(0.f, 0.f, 0.f, 0.f);
  float4 acc1 = make_float4(0.f, 0.f, 0.f, 0.f);
  auto do_edge = [&](unsigned int p, float4& acc) {
    int tq = (int)(p & 8191u);
    int r = (int)(p >> 13);
    h4 tw = *(const h4*)&tabh[(size_t)tq * HID + sl * 4];
    h4 xr = *(const h4*)&x16[(size_t)r * HID + sl * 4];
    acc.x = fmaf((float)xr.x, (float)tw.x, acc.x);
    acc.y = fmaf((float)xr.y, (float)tw.y, acc.y);
    acc.z = fmaf((float)xr.z, (float)tw.z, acc.z);
    acc.w = fmaf((float)xr.w, (float)tw.w, acc.w);
  };
  int i = s;
  for (; i + 8 <= e_end; i += 8) {
    unsigned int p0 = payload[i + half];
    unsigned int p1 = payload[i + 2 + half];
    unsigned int p2 = payload[i + 4 + half];
    unsigned int p3 = payload[i + 6 + half];
    do_edge(p0, acc0);
    do_edge(p1, acc1);
    do_edge(p2, acc0);
    do_edge(p3, acc1);
  }
  for (; i < e_end; i += 2) {
    int e = i + half;
    if (e < e_end) do_edge(payload[e], acc0);
  }
  acc0.x += acc1.x; acc0.y += acc1.y; acc0.z += acc1.z; acc0.w += acc1.w;
  acc0.x += __shfl_xor(acc0.x, 32);
  acc0.y += __shfl_xor(acc0.y, 32);
  acc0.z += __shfl_xor(acc0.z, 32);
  acc0.w += __shfl_xor(acc0.w, 32);
  if (half == 0) {
    h4 o;
    o.x = (_Float16)acc0.x; o.y = (_Float16)acc0.y;
    o.z = (_Float16)acc0.z; o.w = (_Float16)acc0.w;
    *(h4*)&agg16[(size_t)a * HID + sl * 4] = o;
  }
}

// ---- per-atom energy: e[a] = ssp(h[a]@o1w + o1b) . o2w
__global__ __launch_bounds__(256) void atom_energy_k(
    const float* __restrict__ h, const float* __restrict__ o1w,
    const float* __restrict__ o1b, const float* __restrict__ o2w,
    float* __restrict__ e, int N) {
  __shared__ float xs[64 * HID];
  int t = threadIdx.x;
  int a0 = blockIdx.x * 64;
#pragma unroll
  for (int p = 0; p < 8; p++) {
    int fi = t + p * 256;
    int a = a0 + (fi >> 5);
    float4 v = make_float4(0.f, 0.f, 0.f, 0.f);
    if (a < N) v = ((const float4*)h)[(size_t)a * 32 + (fi & 31)];
    ((float4*)xs)[fi] = v;
  }
  __syncthreads();
  int jg = t & 15;
  int ar = t >> 4;
  float4 acc[4];
#pragma unroll
  for (int i = 0; i < 4; i++) acc[i] = make_float4(0.f, 0.f, 0.f, 0.f);
  const float4* Wv = (const float4*)o1w;
  for (int k = 0; k < HID; k += 4) {
    float4 w0 = Wv[(k + 0) * 16 + jg];
    float4 w1 = Wv[(k + 1) * 16 + jg];
    float4 w2 = Wv[(k + 2) * 16 + jg];
    float4 w3 = Wv[(k + 3) * 16 + jg];
#pragma unroll
    for (int i = 0; i < 4; i++) {
      float4 xv = *(const float4*)&xs[(ar * 4 + i) * HID + k];
      float4 a4 = acc[i];
      fma4(a4, xv.x, w0);
      fma4(a4, xv.y, w1);
      fma4(a4, xv.z, w2);
      fma4(a4, xv.w, w3);
      acc[i] = a4;
    }
  }
  float4 b = ((const float4*)o1b)[jg];
  float4 ow = ((const float4*)o2w)[jg];
#pragma unroll
  for (int i = 0; i < 4; i++) {
    float4 v = acc[i];
    float y = sspf(v.x + b.x) * ow.x + sspf(v.y + b.y) * ow.y +
              sspf(v.z + b.z) * ow.z + sspf(v.w + b.w) * ow.w;
    y += __shfl_xor(y, 1);
    y += __shfl_xor(y, 2);
    y += __shfl_xor(y, 4);
    y += __shfl_xor(y, 8);
    int a = a0 + ar * 4 + i;
    if (jg == 0 && a < N) e[a] = y;
  }
}

__global__ __launch_bounds__(256) void seg_sum_k(
    const float* __restrict__ e, const int* __restrict__ batch,
    const float* __restrict__ o2b, float* __restrict__ out, int N) {
  int a = blockIdx.x * 256 + threadIdx.x;
  if (a >= N) return;
  atomicAdd(&out[batch[a]], e[a] + o2b[0]);
}

extern "C" void kernel_launch(void* const* d_in, const int* in_sizes, int n_in,
                              void* d_out, int out_size, void* d_ws, size_t ws_size,
                              hipStream_t stream) {
  const int* z = (const int*)d_in[0];
  const float* pos = (const float*)d_in[1];
  const int* batch = (const int*)d_in[2];
  const int* eidx = (const int*)d_in[3];
  const float* emb = (const float*)d_in[4];
  const float* mlp1_w = (const float*)d_in[5];
  const float* mlp1_b = (const float*)d_in[6];
  const float* mlp2_w = (const float*)d_in[7];
  const float* mlp2_b = (const float*)d_in[8];
  const float* lin1_w = (const float*)d_in[9];
  const float* lin2_w = (const float*)d_in[10];
  const float* lin2_b = (const float*)d_in[11];
  const float* int_w = (const float*)d_in[12];
  const float* int_b = (const float*)d_in[13];
  const float* out1_w = (const float*)d_in[14];
  const float* out1_b = (const float*)d_in[15];
  const float* out2_w = (const float*)d_in[16];
  const float* out2_b = (const float*)d_in[17];
  float* out = (float*)d_out;

  const int N = in_sizes[0];
  const int E = in_sizes[3] / 2;
  const int* row = eidx;
  const int* col = eidx + E;
  const int nbuck = (N + 63) / 64;

  char* ws = (char*)d_ws;
  size_t off = 0;
  auto alloc = [&](size_t bytes) -> void* {
    void* p = ws + off;
    off = (off + bytes + 255) & ~(size_t)255;
    return p;
  };
  float* h = (float*)alloc((size_t)N * HID * 4);
  _Float16* x16 = (_Float16*)alloc((size_t)N * HID * 2);
  // tmp (uint64/edge, scatter staging) aliases agg16 (dead until after scatterB)
  size_t agg_bytes = (size_t)N * HID * 2;
  size_t tmp_bytes = (size_t)E * 8 + 16;
  void* agg_union = alloc(agg_bytes > tmp_bytes ? agg_bytes : tmp_bytes);
  _Float16* agg16 = (_Float16*)agg_union;
  unsigned long long* tmp = (unsigned long long*)agg_union;
  int* tq = (int*)alloc((size_t)E * 4);
  unsigned int* payload = (unsigned int*)alloc((size_t)E * 4 + 16);
  int* starts = (int*)alloc((size_t)(N + 1) * 4);
  int* bcount = (int*)alloc((size_t)nbuck * 4);
  int* bstart = (int*)alloc((size_t)(nbuck + 1) * 4);
  int* bcur = (int*)alloc((size_t)nbuck * 4);
  float* tab = (float*)alloc((size_t)3 * TBL * HID * 4);
  _Float16* tabh = (_Float16*)alloc((size_t)3 * TBL2 * HID * 2);
  _Float16* Wt9 = (_Float16*)alloc((size_t)9 * HID * HID * 2);
  float* e_atom = (float*)alloc((size_t)N * 4);
  (void)ws_size;

  hipMemsetAsync(bcount, 0, (size_t)nbuck * 4, stream);
  hipMemsetAsync(out, 0, (size_t)out_size * 4, stream);

  build_table_k<<<3 * TBL, 128, 0, stream>>>(mlp1_w, mlp1_b, mlp2_w, mlp2_b, tab);
  upsample_k<<<(3 * TBL2 * HID + 255) / 256, 256, 0, stream>>>(tab, tabh);
  wtrans9_k<<<9, 256, 0, stream>>>(lin1_w, lin2_w, int_w, Wt9);
  emb_gather_k<<<(N * 32 + 255) / 256, 256, 0, stream>>>(z, emb, h, N);
  edge_prep_k<<<(E + 2047) / 2048, 256, 0, stream>>>(row, col, pos, tq, bcount, E, nbuck);
  bucket_scan_k<<<1, 256, 0, stream>>>(bcount, bstart, bcur, nbuck, starts, N);
  scatterA_k<<<(E + 2047) / 2048, 256, 0, stream>>>(row, col, tq, bcur, tmp, E, nbuck);
  scatterB_k<<<nbuck, 256, 0, stream>>>(tmp, bstart, starts, payload, N);

  int gemm_grid = (N + 63) / 64;
  for (int l = 0; l < 3; l++) {
    const _Float16* W1t = Wt9 + (size_t)l * HID * HID;
    const _Float16* W2t = Wt9 + (size_t)(3 + l) * HID * HID;
    const _Float16* W3t = Wt9 + (size_t)(6 + l) * HID * HID;
    mfma_lin1_k<<<gemm_grid, 256, 0, stream>>>(h, W1t, x16, N);
    aggregate_k<<<(N + 3) / 4, 256, 0, stream>>>(starts, payload, x16,
                                                 tabh + (size_t)l * TBL2 * HID, agg16, N);
    mfma_fused23_k<<<gemm_grid, 256, 0, stream>>>(agg16, W2t, lin2_b + (size_t)l * HID,
                                                  W3t, int_b + (size_t)l * HID, h, N);
  }
  atom_energy_k<<<gemm_grid, 256, 0, stream>>>(h, out1_w, out1_b, out2_w, e_atom, N);
  seg_sum_k<<<(N + 255) / 256, 256, 0, stream>>>(e_atom, batch, out2_b, out, N);
}

// Round 7
// 586.773 us; speedup vs baseline: 2.5594x; 1.0876x over previous
//
#include <hip/hip_runtime.h>
#include <math.h>

#define HID 128
#define NGAUSS 50
#define TBL 2048
#define TBL2 8192
#define DMAX 8.6605f
#define LDX 136   // fp16 row pitch for MFMA LDS tiles (pad 8 halves)

typedef _Float16 h2 __attribute__((ext_vector_type(2)));
typedef _Float16 h4 __attribute__((ext_vector_type(4)));
typedef _Float16 f16x8 __attribute__((ext_vector_type(8)));
typedef float f32x4 __attribute__((ext_vector_type(4)));

__device__ __forceinline__ float sspf(float x) {
  float ax = fabsf(x);
  return fmaxf(x, 0.0f) + log1pf(expf(-ax)) - 0.69314718055994530942f;
}

// ---- Build W(d) lookup table (fp32, coarse): tab[l][ti][j]
__global__ __launch_bounds__(128) void build_table_k(
    const float* __restrict__ w1, const float* __restrict__ b1,
    const float* __restrict__ w2, const float* __restrict__ b2,
    float* __restrict__ tab) {
  int l = blockIdx.x >> 11;
  int ti = blockIdx.x & (TBL - 1);
  int j = threadIdx.x;
  __shared__ float rbf[NGAUSS];
  __shared__ float v1[HID];
  const float step = DMAX / (float)(TBL - 1);
  float d = ti * step;
  if (j < NGAUSS) {
    const float gstep = 10.0f / 49.0f;
    const float gcoeff = -12.005f;
    float diff = d - j * gstep;
    rbf[j] = expf(gcoeff * diff * diff);
  }
  __syncthreads();
  float s = b1[l * HID + j];
  const float* w1p = w1 + l * NGAUSS * HID + j;
  for (int g = 0; g < NGAUSS; g++) s = fmaf(rbf[g], w1p[g * HID], s);
  v1[j] = sspf(s);
  __syncthreads();
  float s2 = b2[l * HID + j];
  const float* w2p = w2 + l * HID * HID + j;
  for (int k = 0; k < HID; k++) s2 = fmaf(v1[k], w2p[k * HID], s2);
  float C = 0.5f * (cosf(d * 0.3141592653589793f) + 1.0f);
  tab[((size_t)l * TBL + ti) * HID + j] = s2 * C;
}

// ---- upsample coarse fp32 lerp table -> fine fp16 nearest table [l][TBL2][HID]
__global__ __launch_bounds__(256) void upsample_k(
    const float* __restrict__ tab, _Float16* __restrict__ tabh) {
  int idx = blockIdx.x * 256 + threadIdx.x;
  if (idx >= 3 * TBL2 * HID) return;
  int ch = idx & 127;
  int i = (idx >> 7) & (TBL2 - 1);
  int l = idx >> 20;
  float t = (float)i * ((float)(TBL - 1) / (float)(TBL2 - 1));
  int i0 = min((int)t, TBL - 2);
  float f = t - (float)i0;
  const float* base = tab + ((size_t)l * TBL + i0) * HID + ch;
  tabh[idx] = (_Float16)fmaf(f, base[HID] - base[0], base[0]);
}

// ---- transpose+convert 9 128x128 weights + out1_w (128x64) to fp16 Wt[n][k]
__global__ __launch_bounds__(256) void wtrans10_k(
    const float* __restrict__ lin1, const float* __restrict__ lin2,
    const float* __restrict__ intw, const float* __restrict__ out1w,
    _Float16* __restrict__ out) {
  int b = blockIdx.x;
  __shared__ _Float16 tile[128 * 130];
  int t = threadIdx.x;
  if (b < 9) {
    const float* src = (b < 3 ? lin1 : (b < 6 ? lin2 : intw)) + (size_t)(b % 3) * HID * HID;
    _Float16* dst = out + (size_t)b * HID * HID;
    for (int i = t; i < HID * HID; i += 256) tile[(i >> 7) * 130 + (i & 127)] = (_Float16)src[i];
    __syncthreads();
    for (int i = t; i < HID * HID; i += 256) dst[i] = tile[(i & 127) * 130 + (i >> 7)];
  } else {
    _Float16* dst = out + (size_t)9 * HID * HID;
    for (int i = t; i < 128 * 64; i += 256) tile[(i >> 6) * 66 + (i & 63)] = (_Float16)out1w[i];
    __syncthreads();
    for (int i = t; i < 64 * 128; i += 256) dst[i] = tile[(i & 127) * 66 + (i >> 7)];
  }
}

// ---- bucket (col>>6) histogram, LDS-aggregated
__global__ __launch_bounds__(256) void bcount_k(
    const int* __restrict__ col, int* __restrict__ bcount, int E, int nbuck) {
  __shared__ int hist[1024];
  int t = threadIdx.x;
  int e0 = blockIdx.x * 2048;
  for (int j = t; j < nbuck; j += 256) hist[j] = 0;
  __syncthreads();
#pragma unroll
  for (int u = 0; u < 8; u++) {
    int e = e0 + u * 256 + t;
    if (e < E) atomicAdd(&hist[col[e] >> 6], 1);
  }
  __syncthreads();
  for (int j = t; j < nbuck; j += 256)
    if (hist[j]) atomicAdd(&bcount[j], hist[j]);
}

// ---- exclusive scan of bucket counts (single block)
__global__ __launch_bounds__(256) void bucket_scan_k(
    const int* __restrict__ bcount, int* __restrict__ bstart,
    int* __restrict__ bcur, int nbuck, int* __restrict__ starts, int N) {
  __shared__ int sh[256];
  int t = threadIdx.x;
  int chunk = (nbuck + 255) / 256;
  int b0 = t * chunk;
  int c[8];
  int s = 0;
  for (int j = 0; j < chunk; j++) {
    int idx = b0 + j;
    int v = (idx < nbuck) ? bcount[idx] : 0;
    c[j] = v;
    s += v;
  }
  sh[t] = s;
  __syncthreads();
  for (int o = 1; o < 256; o <<= 1) {
    int v = (t >= o) ? sh[t - o] : 0;
    __syncthreads();
    sh[t] += v;
    __syncthreads();
  }
  int p = (t == 0) ? 0 : sh[t - 1];
  for (int j = 0; j < chunk; j++) {
    int idx = b0 + j;
    if (idx < nbuck) {
      bstart[idx] = p;
      bcur[idx] = p;
      p += c[j];
    }
  }
  if (t == 255) {
    bstart[nbuck] = p;
    starts[N] = p;
  }
}

// ---- level-1 scatter: distance inline, key64 into 64-atom bucket chunks
__global__ __launch_bounds__(256) void scatterA_k(
    const int* __restrict__ row, const int* __restrict__ col,
    const float* __restrict__ pos, int* __restrict__ bcur,
    unsigned long long* __restrict__ tmp, int E, int nbuck) {
  __shared__ int hist[1024];
  __shared__ int base[1024];
  int t = threadIdx.x;
  int e0 = blockIdx.x * 2048;
  for (int j = t; j < nbuck; j += 256) hist[j] = 0;
  __syncthreads();
  int bkt[8];
  int rnk[8];
  unsigned long long key[8];
#pragma unroll
  for (int u = 0; u < 8; u++) {
    int e = e0 + u * 256 + t;
    bkt[u] = -1;
    if (e < E) {
      int r = row[e], c = col[e];
      float dx = pos[r * 3 + 0] - pos[c * 3 + 0];
      float dy = pos[r * 3 + 1] - pos[c * 3 + 1];
      float dz = pos[r * 3 + 2] - pos[c * 3 + 2];
      float d = sqrtf(dx * dx + dy * dy + dz * dz);
      const float inv2 = (float)(TBL2 - 1) / DMAX;
      int q = min((int)(d * inv2 + 0.5f), TBL2 - 1);
      unsigned int pay = ((unsigned int)r << 13) | (unsigned int)q;
      key[u] = ((unsigned long long)pay << 6) | (unsigned long long)(c & 63);
      bkt[u] = c >> 6;
      rnk[u] = atomicAdd(&hist[bkt[u]], 1);
    }
  }
  __syncthreads();
  for (int j = t; j < nbuck; j += 256)
    base[j] = hist[j] ? atomicAdd(&bcur[j], hist[j]) : 0;
  __syncthreads();
#pragma unroll
  for (int u = 0; u < 8; u++)
    if (bkt[u] >= 0) tmp[(size_t)base[bkt[u]] + rnk[u]] = key[u];
}

// ---- level-2: per-bucket per-atom counts -> starts, then local scatter
__global__ __launch_bounds__(256) void scatterB_k(
    const unsigned long long* __restrict__ tmp, const int* __restrict__ bstart,
    int* __restrict__ starts, unsigned int* __restrict__ payload, int N) {
  int j = blockIdx.x;
  int t = threadIdx.x;
  __shared__ int cnt[64];
  __shared__ int cur[64];
  int rs = bstart[j], re = bstart[j + 1];
  if (t < 64) cnt[t] = 0;
  __syncthreads();
  for (int e = rs + t; e < re; e += 256)
    atomicAdd(&cnt[(int)(tmp[e] & 63)], 1);
  __syncthreads();
  if (t < 64) {
    int mine = cnt[t];
    int v = mine;
    for (int o = 1; o < 64; o <<= 1) {
      int u = __shfl_up(v, o, 64);
      if (t >= o) v += u;
    }
    int excl = v - mine;
    int c = j * 64 + t;
    if (c < N) starts[c] = rs + excl;
    cur[t] = rs + excl;
  }
  __syncthreads();
  for (int e = rs + t; e < re; e += 256) {
    unsigned long long k = tmp[e];
    int p = atomicAdd(&cur[(int)(k & 63)], 1);
    payload[p] = (unsigned int)(k >> 6);
  }
}

// ---- layer-0: h = emb[z] (write) and x16 = h @ W1_0 (MFMA)
__global__ __launch_bounds__(256) void lin1_emb_k(
    const int* __restrict__ z, const float* __restrict__ emb,
    const _Float16* __restrict__ W1t, float* __restrict__ h,
    _Float16* __restrict__ x16, int N) {
  __shared__ __align__(16) _Float16 Xs[64 * LDX];
  __shared__ __align__(16) _Float16 Ws[128 * LDX];
  __shared__ int zi[64];
  int t = threadIdx.x;
  int a0 = blockIdx.x * 64;
  if (t < 64) zi[t] = (a0 + t < N) ? z[a0 + t] : 0;
  __syncthreads();
#pragma unroll
  for (int p = 0; p < 8; p++) {
    int fi = t + p * 256;
    int a = fi >> 5, kg = fi & 31;
    float4 v = make_float4(0.f, 0.f, 0.f, 0.f);
    if (a0 + a < N) {
      v = ((const float4*)emb)[(size_t)zi[a] * 32 + kg];
      ((float4*)h)[(size_t)(a0 + a) * 32 + kg] = v;
    }
    h4 o;
    o.x = (_Float16)v.x; o.y = (_Float16)v.y;
    o.z = (_Float16)v.z; o.w = (_Float16)v.w;
    *(h4*)&Xs[a * LDX + kg * 4] = o;
  }
#pragma unroll
  for (int p = 0; p < 8; p++) {
    int si = t + p * 256;
    int n = si >> 4, kg = si & 15;
    *(uint4*)&Ws[n * LDX + kg * 8] = ((const uint4*)W1t)[si];
  }
  __syncthreads();
  int lane = t & 63;
  int w = t >> 6;
  int mrow = lane & 15, quad = lane >> 4;
  f32x4 zero = {0.f, 0.f, 0.f, 0.f};
  f32x4 acc[8];
#pragma unroll
  for (int i = 0; i < 8; i++) acc[i] = zero;
#pragma unroll
  for (int kk = 0; kk < 4; kk++) {
    f16x8 af = *(const f16x8*)&Xs[(w * 16 + mrow) * LDX + kk * 32 + quad * 8];
#pragma unroll
    for (int nt = 0; nt < 8; nt++) {
      f16x8 bf = *(const f16x8*)&Ws[(nt * 16 + mrow) * LDX + kk * 32 + quad * 8];
      acc[nt] = __builtin_amdgcn_mfma_f32_16x16x32_f16(af, bf, acc[nt], 0, 0, 0);
    }
  }
  __syncthreads();
#pragma unroll
  for (int nt = 0; nt < 8; nt++)
#pragma unroll
    for (int r = 0; r < 4; r++)
      Xs[(w * 16 + quad * 4 + r) * LDX + nt * 16 + mrow] = (_Float16)acc[nt][r];
  __syncthreads();
#pragma unroll
  for (int p = 0; p < 4; p++) {
    int ci = t + p * 256;
    int a = ci >> 4, kg = ci & 15;
    if (a0 + a < N)
      ((uint4*)x16)[(size_t)(a0 + a) * 16 + kg] = *(uint4*)&Xs[a * LDX + kg * 8];
  }
}

// ---- mid layers: h' = h + ssp(agg@W2+b2)@W3+b3 (write h), x16 = h' @ W1next
__global__ __launch_bounds__(256) void fused_mid_k(
    const _Float16* __restrict__ agg16, const _Float16* __restrict__ W2t,
    const float* __restrict__ b2, const _Float16* __restrict__ W3t,
    const float* __restrict__ b3, float* __restrict__ h,
    const _Float16* __restrict__ W1nt, _Float16* __restrict__ x16, int N) {
  __shared__ __align__(16) _Float16 Xs[64 * LDX];
  __shared__ __align__(16) _Float16 Ws[128 * LDX];
  float* Fs = (float*)Ws;   // 64 x (pitch 132) fp32, overlaps Ws
  int t = threadIdx.x;
  int a0 = blockIdx.x * 64;
#pragma unroll
  for (int p = 0; p < 4; p++) {
    int ci = t + p * 256;
    int a = ci >> 4, kg = ci & 15;
    uint4 v = make_uint4(0, 0, 0, 0);
    if (a0 + a < N) v = ((const uint4*)agg16)[(size_t)(a0 + a) * 16 + kg];
    *(uint4*)&Xs[a * LDX + kg * 8] = v;
  }
#pragma unroll
  for (int p = 0; p < 8; p++) {
    int si = t + p * 256;
    int n = si >> 4, kg = si & 15;
    *(uint4*)&Ws[n * LDX + kg * 8] = ((const uint4*)W2t)[si];
  }
  __syncthreads();
  int lane = t & 63;
  int w = t >> 6;
  int mrow = lane & 15, quad = lane >> 4;
  f32x4 zero = {0.f, 0.f, 0.f, 0.f};
  f32x4 acc[8];
#pragma unroll
  for (int i = 0; i < 8; i++) acc[i] = zero;
#pragma unroll
  for (int kk = 0; kk < 4; kk++) {
    f16x8 af = *(const f16x8*)&Xs[(w * 16 + mrow) * LDX + kk * 32 + quad * 8];
#pragma unroll
    for (int nt = 0; nt < 8; nt++) {
      f16x8 bf = *(const f16x8*)&Ws[(nt * 16 + mrow) * LDX + kk * 32 + quad * 8];
      acc[nt] = __builtin_amdgcn_mfma_f32_16x16x32_f16(af, bf, acc[nt], 0, 0, 0);
    }
  }
  float b2r[8];
#pragma unroll
  for (int nt = 0; nt < 8; nt++) b2r[nt] = b2[nt * 16 + mrow];
  __syncthreads();
#pragma unroll
  for (int nt = 0; nt < 8; nt++)
#pragma unroll
    for (int r = 0; r < 4; r++)
      Xs[(w * 16 + quad * 4 + r) * LDX + nt * 16 + mrow] = (_Float16)sspf(acc[nt][r] + b2r[nt]);
#pragma unroll
  for (int p = 0; p < 8; p++) {
    int si = t + p * 256;
    int n = si >> 4, kg = si & 15;
    *(uint4*)&Ws[n * LDX + kg * 8] = ((const uint4*)W3t)[si];
  }
  __syncthreads();
#pragma unroll
  for (int i = 0; i < 8; i++) acc[i] = zero;
#pragma unroll
  for (int kk = 0; kk < 4; kk++) {
    f16x8 af = *(const f16x8*)&Xs[(w * 16 + mrow) * LDX + kk * 32 + quad * 8];
#pragma unroll
    for (int nt = 0; nt < 8; nt++) {
      f16x8 bf = *(const f16x8*)&Ws[(nt * 16 + mrow) * LDX + kk * 32 + quad * 8];
      acc[nt] = __builtin_amdgcn_mfma_f32_16x16x32_f16(af, bf, acc[nt], 0, 0, 0);
    }
  }
  float b3r[8];
#pragma unroll
  for (int nt = 0; nt < 8; nt++) b3r[nt] = b3[nt * 16 + mrow];
  __syncthreads();   // done reading Xs/Ws
  // stash GEMM2 result (+b3) in fp32 LDS (row-major)
#pragma unroll
  for (int nt = 0; nt < 8; nt++)
#pragma unroll
    for (int r = 0; r < 4; r++)
      Fs[(w * 16 + quad * 4 + r) * 132 + nt * 16 + mrow] = acc[nt][r] + b3r[nt];
  __syncthreads();
  // h' = h + Fs (vectorized); stage h' fp16 into Xs as GEMM3's A
#pragma unroll
  for (int p = 0; p < 8; p++) {
    int ci = t + p * 256;
    int a = ci >> 5, kg = ci & 31;
    float4 v = *(float4*)&Fs[a * 132 + kg * 4];
    if (a0 + a < N) {
      float4 ho = ((const float4*)h)[(size_t)(a0 + a) * 32 + kg];
      v.x += ho.x; v.y += ho.y; v.z += ho.z; v.w += ho.w;
      ((float4*)h)[(size_t)(a0 + a) * 32 + kg] = v;
    }
    h4 o;
    o.x = (_Float16)v.x; o.y = (_Float16)v.y;
    o.z = (_Float16)v.z; o.w = (_Float16)v.w;
    *(h4*)&Xs[a * LDX + kg * 4] = o;
  }
  __syncthreads();   // done reading Fs
#pragma unroll
  for (int p = 0; p < 8; p++) {
    int si = t + p * 256;
    int n = si >> 4, kg = si & 15;
    *(uint4*)&Ws[n * LDX + kg * 8] = ((const uint4*)W1nt)[si];
  }
  __syncthreads();
#pragma unroll
  for (int i = 0; i < 8; i++) acc[i] = zero;
#pragma unroll
  for (int kk = 0; kk < 4; kk++) {
    f16x8 af = *(const f16x8*)&Xs[(w * 16 + mrow) * LDX + kk * 32 + quad * 8];
#pragma unroll
    for (int nt = 0; nt < 8; nt++) {
      f16x8 bf = *(const f16x8*)&Ws[(nt * 16 + mrow) * LDX + kk * 32 + quad * 8];
      acc[nt] = __builtin_amdgcn_mfma_f32_16x16x32_f16(af, bf, acc[nt], 0, 0, 0);
    }
  }
  __syncthreads();
#pragma unroll
  for (int nt = 0; nt < 8; nt++)
#pragma unroll
    for (int r = 0; r < 4; r++)
      Xs[(w * 16 + quad * 4 + r) * LDX + nt * 16 + mrow] = (_Float16)acc[nt][r];
  __syncthreads();
#pragma unroll
  for (int p = 0; p < 4; p++) {
    int ci = t + p * 256;
    int a = ci >> 4, kg = ci & 15;
    if (a0 + a < N)
      ((uint4*)x16)[(size_t)(a0 + a) * 16 + kg] = *(uint4*)&Xs[a * LDX + kg * 8];
  }
}

// ---- last layer: h' (not stored) -> e = ssp(h'@o1w+o1b).o2w -> atomic out[batch]
__global__ __launch_bounds__(256) void fused_last_k(
    const _Float16* __restrict__ agg16, const _Float16* __restrict__ W2t,
    const float* __restrict__ b2, const _Float16* __restrict__ W3t,
    const float* __restrict__ b3, const float* __restrict__ h,
    const _Float16* __restrict__ Wo1t, const float* __restrict__ o1b,
    const float* __restrict__ o2w, const float* __restrict__ o2b,
    const int* __restrict__ batch, float* __restrict__ out, int N) {
  __shared__ __align__(16) _Float16 Xs[64 * LDX];
  __shared__ __align__(16) _Float16 Ws[128 * LDX];
  float* Fs = (float*)Ws;
  int t = threadIdx.x;
  int a0 = blockIdx.x * 64;
#pragma unroll
  for (int p = 0; p < 4; p++) {
    int ci = t + p * 256;
    int a = ci >> 4, kg = ci & 15;
    uint4 v = make_uint4(0, 0, 0, 0);
    if (a0 + a < N) v = ((const uint4*)agg16)[(size_t)(a0 + a) * 16 + kg];
    *(uint4*)&Xs[a * LDX + kg * 8] = v;
  }
#pragma unroll
  for (int p = 0; p < 8; p++) {
    int si = t + p * 256;
    int n = si >> 4, kg = si & 15;
    *(uint4*)&Ws[n * LDX + kg * 8] = ((const uint4*)W2t)[si];
  }
  __syncthreads();
  int lane = t & 63;
  int w = t >> 6;
  int mrow = lane & 15, quad = lane >> 4;
  f32x4 zero = {0.f, 0.f, 0.f, 0.f};
  f32x4 acc[8];
#pragma unroll
  for (int i = 0; i < 8; i++) acc[i] = zero;
#pragma unroll
  for (int kk = 0; kk < 4; kk++) {
    f16x8 af = *(const f16x8*)&Xs[(w * 16 + mrow) * LDX + kk * 32 + quad * 8];
#pragma unroll
    for (int nt = 0; nt < 8; nt++) {
      f16x8 bf = *(const f16x8*)&Ws[(nt * 16 + mrow) * LDX + kk * 32 + quad * 8];
      acc[nt] = __builtin_amdgcn_mfma_f32_16x16x32_f16(af, bf, acc[nt], 0, 0, 0);
    }
  }
  float b2r[8];
#pragma unroll
  for (int nt = 0; nt < 8; nt++) b2r[nt] = b2[nt * 16 + mrow];
  __syncthreads();
#pragma unroll
  for (int nt = 0; nt < 8; nt++)
#pragma unroll
    for (int r = 0; r < 4; r++)
      Xs[(w * 16 + quad * 4 + r) * LDX + nt * 16 + mrow] = (_Float16)sspf(acc[nt][r] + b2r[nt]);
#pragma unroll
  for (int p = 0; p < 8; p++) {
    int si = t + p * 256;
    int n = si >> 4, kg = si & 15;
    *(uint4*)&Ws[n * LDX + kg * 8] = ((const uint4*)W3t)[si];
  }
  __syncthreads();
#pragma unroll
  for (int i = 0; i < 8; i++) acc[i] = zero;
#pragma unroll
  for (int kk = 0; kk < 4; kk++) {
    f16x8 af = *(const f16x8*)&Xs[(w * 16 + mrow) * LDX + kk * 32 + quad * 8];
#pragma unroll
    for (int nt = 0; nt < 8; nt++) {
      f16x8 bf = *(const f16x8*)&Ws[(nt * 16 + mrow) * LDX + kk * 32 + quad * 8];
      acc[nt] = __builtin_amdgcn_mfma_f32_16x16x32_f16(af, bf, acc[nt], 0, 0, 0);
    }
  }
  float b3r[8];
#pragma unroll
  for (int nt = 0; nt < 8; nt++) b3r[nt] = b3[nt * 16 + mrow];
  __syncthreads();
#pragma unroll
  for (int nt = 0; nt < 8; nt++)
#pragma unroll
    for (int r = 0; r < 4; r++)
      Fs[(w * 16 + quad * 4 + r) * 132 + nt * 16 + mrow] = acc[nt][r] + b3r[nt];
  __syncthreads();
#pragma unroll
  for (int p = 0; p < 8; p++) {
    int ci = t + p * 256;
    int a = ci >> 5, kg = ci & 31;
    float4 v = *(float4*)&Fs[a * 132 + kg * 4];
    if (a0 + a < N) {
      float4 ho = ((const float4*)h)[(size_t)(a0 + a) * 32 + kg];
      v.x += ho.x; v.y += ho.y; v.z += ho.z; v.w += ho.w;
    }
    h4 o;
    o.x = (_Float16)v.x; o.y = (_Float16)v.y;
    o.z = (_Float16)v.z; o.w = (_Float16)v.w;
    *(h4*)&Xs[a * LDX + kg * 4] = o;
  }
  __syncthreads();
#pragma unroll
  for (int p = 0; p < 4; p++) {   // out1 weights: 64 rows only
    int si = t + p * 256;
    int n = si >> 4, kg = si & 15;
    *(uint4*)&Ws[n * LDX + kg * 8] = ((const uint4*)Wo1t)[si];
  }
  __syncthreads();
#pragma unroll
  for (int i = 0; i < 4; i++) acc[i] = zero;
#pragma unroll
  for (int kk = 0; kk < 4; kk++) {
    f16x8 af = *(const f16x8*)&Xs[(w * 16 + mrow) * LDX + kk * 32 + quad * 8];
#pragma unroll
    for (int nt = 0; nt < 4; nt++) {
      f16x8 bf = *(const f16x8*)&Ws[(nt * 16 + mrow) * LDX + kk * 32 + quad * 8];
      acc[nt] = __builtin_amdgcn_mfma_f32_16x16x32_f16(af, bf, acc[nt], 0, 0, 0);
    }
  }
  float o2b0 = o2b[0];
  float ss[4] = {0.f, 0.f, 0.f, 0.f};
#pragma unroll
  for (int nt = 0; nt < 4; nt++) {
    float bb = o1b[nt * 16 + mrow];
    float ww = o2w[nt * 16 + mrow];
#pragma unroll
    for (int r = 0; r < 4; r++) ss[r] += sspf(acc[nt][r] + bb) * ww;
  }
#pragma unroll
  for (int r = 0; r < 4; r++) {
    ss[r] += __shfl_xor(ss[r], 1);
    ss[r] += __shfl_xor(ss[r], 2);
    ss[r] += __shfl_xor(ss[r], 4);
    ss[r] += __shfl_xor(ss[r], 8);
    int a = a0 + w * 16 + quad * 4 + r;
    if (mrow == 0 && a < N) atomicAdd(&out[batch[a]], ss[r] + o2b0);
  }
}

// ---- agg16[a] = (fp16) sum_{e: col=a} x16[row_e] * tabh[tq_e]
__global__ __launch_bounds__(256) void aggregate_k(
    const int* __restrict__ starts, const unsigned int* __restrict__ payload,
    const _Float16* __restrict__ x16, const _Float16* __restrict__ tabh,
    _Float16* __restrict__ agg16, int N) {
  int a = blockIdx.x * 4 + (threadIdx.x >> 6);
  if (a >= N) return;
  int lane = threadIdx.x & 63;
  int half = lane >> 5;
  int sl = lane & 31;
  int s = starts[a], e_end = starts[a + 1];
  float4 acc0 = make_float4(0.f, 0.f, 0.f, 0.f);
  float4 acc1 = make_float4(0.f, 0.f, 0.f, 0.f);
  auto do_edge = [&](unsigned int p, float4& acc) {
    int tq = (int)(p & 8191u);
    int r = (int)(p >> 13);
    h4 tw = *(const h4*)&tabh[(size_t)tq * HID + sl * 4];
    h4 xr = *(const h4*)&x16[(size_t)r * HID + sl * 4];
    acc.x = fmaf((float)xr.x, (float)tw.x, acc.x);
    acc.y = fmaf((float)xr.y, (float)tw.y, acc.y);
    acc.z = fmaf((float)xr.z, (float)tw.z, acc.z);
    acc.w = fmaf((float)xr.w, (float)tw.w, acc.w);
  };
  int i = s;
  for (; i + 8 <= e_end; i += 8) {
    unsigned int p0 = payload[i + half];
    unsigned int p1 = payload[i + 2 + half];
    unsigned int p2 = payload[i + 4 + half];
    unsigned int p3 = payload[i + 6 + half];
    do_edge(p0, acc0);
    do_edge(p1, acc1);
    do_edge(p2, acc0);
    do_edge(p3, acc1);
  }
  for (; i < e_end; i += 2) {
    int e = i + half;
    if (e < e_end) do_edge(payload[e], acc0);
  }
  acc0.x += acc1.x; acc0.y += acc1.y; acc0.z += acc1.z; acc0.w += acc1.w;
  acc0.x += __shfl_xor(acc0.x, 32);
  acc0.y += __shfl_xor(acc0.y, 32);
  acc0.z += __shfl_xor(acc0.z, 32);
  acc0.w += __shfl_xor(acc0.w, 32);
  if (half == 0) {
    h4 o;
    o.x = (_Float16)acc0.x; o.y = (_Float16)acc0.y;
    o.z = (_Float16)acc0.z; o.w = (_Float16)acc0.w;
    *(h4*)&agg16[(size_t)a * HID + sl * 4] = o;
  }
}

extern "C" void kernel_launch(void* const* d_in, const int* in_sizes, int n_in,
                              void* d_out, int out_size, void* d_ws, size_t ws_size,
                              hipStream_t stream) {
  const int* z = (const int*)d_in[0];
  const float* pos = (const float*)d_in[1];
  const int* batch = (const int*)d_in[2];
  const int* eidx = (const int*)d_in[3];
  const float* emb = (const float*)d_in[4];
  const float* mlp1_w = (const float*)d_in[5];
  const float* mlp1_b = (const float*)d_in[6];
  const float* mlp2_w = (const float*)d_in[7];
  const float* mlp2_b = (const float*)d_in[8];
  const float* lin1_w = (const float*)d_in[9];
  const float* lin2_w = (const float*)d_in[10];
  const float* lin2_b = (const float*)d_in[11];
  const float* int_w = (const float*)d_in[12];
  const float* int_b = (const float*)d_in[13];
  const float* out1_w = (const float*)d_in[14];
  const float* out1_b = (const float*)d_in[15];
  const float* out2_w = (const float*)d_in[16];
  const float* out2_b = (const float*)d_in[17];
  float* out = (float*)d_out;

  const int N = in_sizes[0];
  const int E = in_sizes[3] / 2;
  const int* row = eidx;
  const int* col = eidx + E;
  const int nbuck = (N + 63) / 64;

  char* ws = (char*)d_ws;
  size_t off = 0;
  auto alloc = [&](size_t bytes) -> void* {
    void* p = ws + off;
    off = (off + bytes + 255) & ~(size_t)255;
    return p;
  };
  float* h = (float*)alloc((size_t)N * HID * 4);
  _Float16* x16 = (_Float16*)alloc((size_t)N * HID * 2);
  size_t agg_bytes = (size_t)N * HID * 2;
  size_t tmp_bytes = (size_t)E * 8 + 16;
  void* agg_union = alloc(agg_bytes > tmp_bytes ? agg_bytes : tmp_bytes);
  _Float16* agg16 = (_Float16*)agg_union;
  unsigned long long* tmp = (unsigned long long*)agg_union;
  unsigned int* payload = (unsigned int*)alloc((size_t)E * 4 + 16);
  int* starts = (int*)alloc((size_t)(N + 1) * 4);
  int* bcount = (int*)alloc((size_t)nbuck * 4);
  int* bstart = (int*)alloc((size_t)(nbuck + 1) * 4);
  int* bcur = (int*)alloc((size_t)nbuck * 4);
  float* tab = (float*)alloc((size_t)3 * TBL * HID * 4);
  _Float16* tabh = (_Float16*)alloc((size_t)3 * TBL2 * HID * 2);
  _Float16* Wt10 = (_Float16*)alloc((size_t)10 * HID * HID * 2);
  (void)ws_size;

  hipMemsetAsync(bcount, 0, (size_t)nbuck * 4, stream);
  hipMemsetAsync(out, 0, (size_t)out_size * 4, stream);

  build_table_k<<<3 * TBL, 128, 0, stream>>>(mlp1_w, mlp1_b, mlp2_w, mlp2_b, tab);
  upsample_k<<<(3 * TBL2 * HID + 255) / 256, 256, 0, stream>>>(tab, tabh);
  wtrans10_k<<<10, 256, 0, stream>>>(lin1_w, lin2_w, int_w, out1_w, Wt10);
  bcount_k<<<(E + 2047) / 2048, 256, 0, stream>>>(col, bcount, E, nbuck);
  bucket_scan_k<<<1, 256, 0, stream>>>(bcount, bstart, bcur, nbuck, starts, N);
  scatterA_k<<<(E + 2047) / 2048, 256, 0, stream>>>(row, col, pos, bcur, tmp, E, nbuck);
  scatterB_k<<<nbuck, 256, 0, stream>>>(tmp, bstart, starts, payload, N);

  int gemm_grid = (N + 63) / 64;
  lin1_emb_k<<<gemm_grid, 256, 0, stream>>>(z, emb, Wt10, h, x16, N);
  for (int l = 0; l < 2; l++) {
    aggregate_k<<<(N + 3) / 4, 256, 0, stream>>>(starts, payload, x16,
                                                 tabh + (size_t)l * TBL2 * HID, agg16, N);
    fused_mid_k<<<gemm_grid, 256, 0, stream>>>(
        agg16, Wt10 + (size_t)(3 + l) * HID * HID, lin2_b + (size_t)l * HID,
        Wt10 + (size_t)(6 + l) * HID * HID, int_b + (size_t)l * HID, h,
        Wt10 + (size_t)(l + 1) * HID * HID, x16, N);
  }
  aggregate_k<<<(N + 3) / 4, 256, 0, stream>>>(starts, payload, x16,
                                               tabh + (size_t)2 * TBL2 * HID, agg16, N);
  fused_last_k<<<gemm_grid, 256, 0, stream>>>(
      agg16, Wt10 + (size_t)5 * HID * HID, lin2_b + (size_t)2 * HID,
      Wt10 + (size_t)8 * HID * HID, int_b + (size_t)2 * HID, h,
      Wt10 + (size_t)9 * HID * HID, out1_b, out2_w, out2_b, batch, out, N);
}